// Round 10
// baseline (6100.522 us; speedup 1.0000x reference)
//
#include <hip/hip_runtime.h>

#define NNODE 1000
#define NBATCH 8
#define SEQL 12
#define NHEAD 8
#define DHEAD 16
#define HID 128
#define NEDGE 16000
#define NROWS (NBATCH*NNODE)   // 8000
#define RPB 16                 // rows per persistent block (R10: halved)
#define NBLK_P 512             // 8 batches x 64 slots; 2 blocks/CU
#define NBLK_B 64              // blocks per batch = barrier width
#define BARSTRIDE 64           // ints between per-batch counters (256 B)
#define PTHREADS 1024
#define ORPB 16
#define NBLK_O (NROWS/ORPB)    // 500
#define DT 0.25f
#define ECAP 768               // LDS edge cache (block mean 256)
#define SPIN_LIMIT 2000000ULL  // 20 ms: transient slowness costs time, not NaN (R6)
#define WSTRIDE 136            // padded K-stride (u16, LDS tiles)
#define HSTR 144               // exchange row stride (u16): 128 fp16 h + 8 f32 el

// bar[] layout (ints), all zeroed by csr_kernel:
//   bat*64 + 0  : per-batch round counter
//   bat*64 + 32 : per-batch XCD mask
//   48          : global XCD mask   (batch0 stride area, unused offsets)
//   56          : startup barrier counter (512-wide)
#define OFF_MASK  32
#define OFF_GMASK 48
#define OFF_GCNT  56
#define HWREG_XCC_ID 6164      // s_getreg imm: id=20 (XCC_ID), offset=0, size=4

// Journal:
// R3 (edge-balanced LDS-atomic gather): 10x regression. REVERTED.
// R4/R6/R9 (deepen gather pipeline, 3 attempts): all blocked by the immovable
//    64-VGPR allocation (spill -> FETCH blowup / NaN / +200us). Lever DEAD;
//    gather stays at R8's 4-deep shape.
// R5 (el precomputed, exchanged with h): 1874 -> 1744. KEPT.
// R7 (ht_bf split + MFMA 2-chain): -> 1733. KEPT.
// R8 (plain loads + per-round buffer_inv): 1731, coherence proven. KEPT.
// R10: occupancy play. fp16 replaces bf16-hi/lo for W/y/h (single matrix,
//    34.8 KB vs 68 KB; y/h mantissa 8x better, W error ~5x below h-quant
//    noise) + GRU weights fp16-in-LDS -> ~55 KB/block -> 2 blocks/CU.
//    512 blocks x 16 rows, 64-wide barriers, 64 gather lanes/row (critical
//    chain halved), MFMA work halved. Decisive counter: OccupancyPercent.

typedef unsigned short u16;
typedef unsigned int   u32;
typedef unsigned long long u64;
typedef __attribute__((ext_vector_type(8))) _Float16 f16x8;
typedef __attribute__((ext_vector_type(4))) float f32x4;
typedef __attribute__((ext_vector_type(4))) unsigned int u32x4;

__device__ __forceinline__ u16 f2h(float f){
  union { _Float16 h; u16 u; } cv; cv.h = (_Float16)f; return cv.u;
}
__device__ __forceinline__ float h2f(u16 u){
  union { _Float16 h; u16 u; } cv; cv.u = u; return (float)cv.h;
}

// ---- exchange primitives ----
// Agent path (MALL point-of-coherence): correct under ANY block->XCD mapping.
__device__ __forceinline__ u64 ld_agent_u64(const u16* p){
  return __hip_atomic_load(reinterpret_cast<const u64*>(p),
                           __ATOMIC_RELAXED, __HIP_MEMORY_SCOPE_AGENT);
}
__device__ __forceinline__ void st_agent_u64(u16* p, u64 v){
  __hip_atomic_store(reinterpret_cast<u64*>(p), v,
                     __ATOMIC_RELAXED, __HIP_MEMORY_SCOPE_AGENT);
}
__device__ __forceinline__ float ld_agent_f32(const float* p){
  u32 v = __hip_atomic_load(reinterpret_cast<const u32*>(p),
                            __ATOMIC_RELAXED, __HIP_MEMORY_SCOPE_AGENT);
  return __uint_as_float(v);
}
__device__ __forceinline__ void st_agent_f32(float* p, float v){
  __hip_atomic_store(reinterpret_cast<u32*>(p), __float_as_uint(v),
                     __ATOMIC_RELAXED, __HIP_MEMORY_SCOPE_AGENT);
}

// L1 invalidate (gfx940+): after the per-round barrier, clears stale h lines
// in THIS CU's vector L1; plain loads then read current L2 (L1 is WT). R8-proven.
__device__ __forceinline__ void inv_l1(){
  asm volatile("buffer_inv sc0\n\ts_waitcnt vmcnt(0)" ::: "memory");
}

// L2-barrier poll: failing CAS executed at the XCD TCC atomic unit returns the
// current counter value — meets the fetch_add increments at the same unit.
__device__ __forceinline__ int poll_l2(int* p){
  int exp = -1;                     // counter is never -1
  __hip_atomic_compare_exchange_strong(p, &exp, -1,
      __ATOMIC_RELAXED, __ATOMIC_RELAXED, __HIP_MEMORY_SCOPE_WORKGROUP);
  return exp;
}

// ---- barriers ----
__device__ __forceinline__ void grid_bar2(int* bar, int target, bool l2){
  __syncthreads();   // drains each wave's stores (vmcnt 0) before arrival
  if (threadIdx.x == 0){
    unsigned long long t0;
    if (l2){
      __hip_atomic_fetch_add(bar, 1, __ATOMIC_RELAXED, __HIP_MEMORY_SCOPE_WORKGROUP);
      t0 = __builtin_amdgcn_s_memrealtime();
      while (poll_l2(bar) < target){
        __builtin_amdgcn_s_sleep(2);
        if (__builtin_amdgcn_s_memrealtime() - t0 > SPIN_LIMIT) break;
      }
    } else {
      __hip_atomic_fetch_add(bar, 1, __ATOMIC_RELEASE, __HIP_MEMORY_SCOPE_AGENT);
      t0 = __builtin_amdgcn_s_memrealtime();
      while (__hip_atomic_load(bar, __ATOMIC_RELAXED, __HIP_MEMORY_SCOPE_AGENT) < target){
        __builtin_amdgcn_s_sleep(2);
        if (__builtin_amdgcn_s_memrealtime() - t0 > SPIN_LIMIT) break;
      }
    }
  }
  __syncthreads();
}

// one-time 512-block agent barrier (orders initial h stores + XCD-mask ORs)
__device__ __forceinline__ void startup_bar(int* cnt){
  __syncthreads();
  if (threadIdx.x == 0){
    __hip_atomic_fetch_add(cnt, 1, __ATOMIC_RELEASE, __HIP_MEMORY_SCOPE_AGENT);
    unsigned long long t0 = __builtin_amdgcn_s_memrealtime();
    while (__hip_atomic_load(cnt, __ATOMIC_RELAXED, __HIP_MEMORY_SCOPE_AGENT) < NBLK_P){
      __builtin_amdgcn_s_sleep(2);
      if (__builtin_amdgcn_s_memrealtime() - t0 > SPIN_LIMIT) break;
    }
  }
  __syncthreads();
}

// copy a 128x128 fp32 matrix global->LDS (out_kernel only)
template<int NT>
__device__ __forceinline__ void load_W(float* Wl, const float* g, int tid){
  #pragma unroll
  for (int c = 0; c < (HID*HID/4)/NT; ++c){
    int e = (c*NT + tid)*4;
    *reinterpret_cast<float4*>(Wl + e) = *reinterpret_cast<const float4*>(g + e);
  }
}

// fp16 copy: W[k][n] fp32 -> Wg[k*128+n] fp16 (GRU path; arena overlay)
__device__ __forceinline__ void load_W_f16(u16* Wg, const float* g, int tid){
  #pragma unroll
  for (int c = 0; c < (HID*HID)/PTHREADS; ++c){
    int e = c*PTHREADS + tid;
    Wg[e] = f2h(g[e]);
  }
}

// fp16 transposed load: W[k][n] fp32 -> Wb[n*WSTRIDE+k] fp16 (MFMA B operand)
__device__ __forceinline__ void load_WT_f16(u16* Wb, const float* g, int tid){
  #pragma unroll
  for (int c = 0; c < 16; ++c){
    int flat = c*PTHREADS + tid;        // = k*128 + n
    int k = flat >> 7, n = flat & 127;
    Wb[n*WSTRIDE + k] = f2h(g[flat]);
  }
}

// one row, 4 cols, fp16 weights in LDS: o[j] = sum_k yt[rs][k]*W[k][fg*4+j]
__device__ __forceinline__ void gemm128_1h(const u16* Wg, const float* yt, int fg, int rs,
                                           float o[4]){
  float a0[4]={0.f,0.f,0.f,0.f};
  #pragma unroll 4
  for (int k=0;k<HID;k+=4){
    float4 ya = *reinterpret_cast<const float4*>(yt + rs*HID + k);
    #pragma unroll
    for (int kk=0;kk<4;++kk){
      const u16* wr = Wg + (k+kk)*HID + fg*4;
      float av = (&ya.x)[kk];
      #pragma unroll
      for (int i=0;i<4;++i) a0[i] = fmaf(h2f(wr[i]), av, a0[i]);
    }
  }
  #pragma unroll
  for (int i=0;i<4;++i) o[i]=a0[i];
}

// two rows (rs, rs+RSTEP), 4 cols, fp32 — out_kernel only
template<int RSTEP>
__device__ __forceinline__ void gemm128(const float* Wl, const float* yt, int fg, int rs,
                                        float o0[4], float o1[4]){
  float a0[4]={0.f,0.f,0.f,0.f}, a1[4]={0.f,0.f,0.f,0.f};
  #pragma unroll 4
  for (int k=0;k<HID;k+=4){
    float4 ya = *reinterpret_cast<const float4*>(yt + rs*HID + k);
    float4 yb = *reinterpret_cast<const float4*>(yt + (rs+RSTEP)*HID + k);
    #pragma unroll
    for (int kk=0;kk<4;++kk){
      const float* wr = Wl + (k+kk)*HID + fg*4;
      float av = (&ya.x)[kk];
      float bv = (&yb.x)[kk];
      #pragma unroll
      for (int i=0;i<4;++i){
        float w = wr[i];
        a0[i] = fmaf(w, av, a0[i]);
        a1[i] = fmaf(w, bv, a1[i]);
      }
    }
  }
  #pragma unroll
  for (int i=0;i<4;++i){ o0[i]=a0[i]; o1[i]=a1[i]; }
}

// pack 8 fp32 -> 8 fp16 into yt[rA][off8..off8+7]
__device__ __forceinline__ void pack_y(u16* yt, int rA, int off8, const float y[8]){
  uint4 w;
  w.x = (u32)f2h(y[0]) | ((u32)f2h(y[1])<<16);
  w.y = (u32)f2h(y[2]) | ((u32)f2h(y[3])<<16);
  w.z = (u32)f2h(y[4]) | ((u32)f2h(y[5])<<16);
  w.w = (u32)f2h(y[6]) | ((u32)f2h(y[7])<<16);
  *reinterpret_cast<uint4*>(yt + rA*WSTRIDE + off8) = w;
}

// per-edge decode (fp16) + attention + register accumulate
__device__ __forceinline__ void edge_acc(const u32x4 q, float el, float erh,
                                         float acc[8], float& sum){
  float hv[8];
  hv[0]=h2f((u16)q[0]); hv[1]=h2f((u16)(q[0]>>16));
  hv[2]=h2f((u16)q[1]); hv[3]=h2f((u16)(q[1]>>16));
  hv[4]=h2f((u16)q[2]); hv[5]=h2f((u16)(q[2]>>16));
  hv[6]=h2f((u16)q[3]); hv[7]=h2f((u16)(q[3]>>16));
  const float x = el + erh;
  const float w = __expf(fminf(fmaxf(x, 0.2f*x), 30.f));
  sum += w;
  #pragma unroll
  for (int i=0;i<8;++i) acc[i] = fmaf(w, hv[i], acc[i]);
}

// gather over this thread's edge range (R8 shape: 4-deep, plain loads).
template<bool L2>
__device__ __forceinline__ void gather_f(const u16* __restrict__ h_rd,
    const int* __restrict__ eptr, int e_lo, int e_hi, int sbase, int off8, int hd,
    float erh, float acc[8], float& sum)
{
  if constexpr (L2){
    int e = e_lo;
    for (; e + 4 <= e_hi; e += 4){
      const u16* r0 = h_rd + (size_t)(sbase + eptr[e+0])*HSTR;
      const u16* r1 = h_rd + (size_t)(sbase + eptr[e+1])*HSTR;
      const u16* r2 = h_rd + (size_t)(sbase + eptr[e+2])*HSTR;
      const u16* r3 = h_rd + (size_t)(sbase + eptr[e+3])*HSTR;
      u32x4 q0 = *reinterpret_cast<const u32x4*>(r0 + off8);
      u32x4 q1 = *reinterpret_cast<const u32x4*>(r1 + off8);
      u32x4 q2 = *reinterpret_cast<const u32x4*>(r2 + off8);
      u32x4 q3 = *reinterpret_cast<const u32x4*>(r3 + off8);
      float x0 = reinterpret_cast<const float*>(r0 + 128)[hd];
      float x1 = reinterpret_cast<const float*>(r1 + 128)[hd];
      float x2 = reinterpret_cast<const float*>(r2 + 128)[hd];
      float x3 = reinterpret_cast<const float*>(r3 + 128)[hd];
      edge_acc(q0, x0, erh, acc, sum);
      edge_acc(q1, x1, erh, acc, sum);
      edge_acc(q2, x2, erh, acc, sum);
      edge_acc(q3, x3, erh, acc, sum);
    }
    for (; e < e_hi; ++e){
      const u16* r = h_rd + (size_t)(sbase + eptr[e])*HSTR;
      u32x4 q = *reinterpret_cast<const u32x4*>(r + off8);
      float x = reinterpret_cast<const float*>(r + 128)[hd];
      edge_acc(q, x, erh, acc, sum);
    }
  } else {
    for (int e = e_lo; e < e_hi; ++e){
      const u16* r = h_rd + (size_t)(sbase + eptr[e])*HSTR;
      const u64 L = ld_agent_u64(r + off8);
      const u64 H = ld_agent_u64(r + off8 + 4);
      const float x = ld_agent_f32(reinterpret_cast<const float*>(r + 128) + hd);
      u32x4 v;
      v[0]=(u32)L; v[1]=(u32)(L>>32); v[2]=(u32)H; v[3]=(u32)(H>>32);
      edge_acc(v, x, erh, acc, sum);
    }
  }
}

// MFMA h-stage (fp16): y tile is 16x128, 8 waves do 1 Mx8 N tiles; waves 8-15
// idle through the MFMA (extra scheduler slots for the co-resident block).
// Two accumulator chains. Wire-stores packed u64 h (4 fp16) + fp32 el.
__device__ __forceinline__ void h_stage(const u16* yt, u16* ht, const u16* Wb,
    int wv, int quad, int lc,
    int fg, int rs, int rsF, int rowF, bool actF, bool l2,
    u16* __restrict__ h_wr, float* er_l, const float ar4[4], const float al4[4])
{
  if (wv < 8){
    f32x4 c0 = {0.f,0.f,0.f,0.f}, c1 = {0.f,0.f,0.f,0.f};
    const u16* arow = yt + lc*WSTRIDE;
    const u16* brow = Wb + (wv*16 + lc)*WSTRIDE;
    #pragma unroll
    for (int k0 = 0; k0 < 4; ++k0){
      const int off = k0*32 + quad*8;
      f16x8 a = *reinterpret_cast<const f16x8*>(arow + off);
      f16x8 b = *reinterpret_cast<const f16x8*>(brow + off);
      if (k0 & 1) c1 = __builtin_amdgcn_mfma_f32_16x16x32_f16(a, b, c1, 0, 0, 0);
      else        c0 = __builtin_amdgcn_mfma_f32_16x16x32_f16(a, b, c0, 0, 0, 0);
    }
    const int col = wv*16 + lc;
    #pragma unroll
    for (int r = 0; r < 4; ++r)
      ht[(quad*4 + r)*WSTRIDE + col] = f2h(c0[r] + c1[r]);
  }
  __syncthreads();              // h fp16 visible block-wide
  const u64 pk = *reinterpret_cast<const u64*>(ht + rsF*WSTRIDE + fg*4);
  if (actF){
    if (l2) *reinterpret_cast<u64*>(h_wr + (size_t)rowF*HSTR + fg*4) = pk;
    else    st_agent_u64(h_wr + (size_t)rowF*HSTR + fg*4, pk);
  }
  const float h0 = h2f((u16)pk),       h1 = h2f((u16)(pk>>16));
  const float h2 = h2f((u16)(pk>>32)), h3 = h2f((u16)(pk>>48));
  float er = 0.f, el = 0.f;
  er = fmaf(h0, ar4[0], er); er = fmaf(h1, ar4[1], er);
  er = fmaf(h2, ar4[2], er); er = fmaf(h3, ar4[3], er);
  el = fmaf(h0, al4[0], el); el = fmaf(h1, al4[1], el);
  el = fmaf(h2, al4[2], el); el = fmaf(h3, al4[3], el);
  er += __shfl_xor(er,1); er += __shfl_xor(er,2);
  el += __shfl_xor(el,1); el += __shfl_xor(el,2);
  if ((fg & 3) == 0 && actF){
    er_l[rsF*NHEAD + (fg>>2)] = er;
    float* elp = reinterpret_cast<float*>(h_wr + (size_t)rowF*HSTR + 128);
    if (l2) elp[fg>>2] = el;
    else    st_agent_f32(elp + (fg>>2), el);
  }
}

// Build CSR (edges sorted by dst); zero the per-batch barrier area.
__global__ void csr_kernel(const int* __restrict__ src, const int* __restrict__ dst,
                           int* __restrict__ row_start, int* __restrict__ edge_src,
                           int* __restrict__ bar){
  __shared__ int cnt[1024];
  __shared__ int scanb[1024];
  __shared__ int cur[1024];
  int tid = threadIdx.x;
  if (tid < NBATCH*BARSTRIDE) bar[tid] = 0;
  cnt[tid] = 0;
  __syncthreads();
  for (int e = tid; e < NEDGE; e += 1024) atomicAdd(&cnt[dst[e]], 1);
  __syncthreads();
  int v = cnt[tid];
  scanb[tid] = v;
  __syncthreads();
  for (int off=1; off<1024; off<<=1){
    int t = (tid >= off) ? scanb[tid-off] : 0;
    __syncthreads();
    scanb[tid] += t;
    __syncthreads();
  }
  int incl = scanb[tid];
  if (tid < NNODE){ cur[tid] = incl - v; row_start[tid+1] = incl; }
  if (tid == 0) row_start[0] = 0;
  __syncthreads();
  for (int e = tid; e < NEDGE; e += 1024){
    int d = dst[e];
    int pos = atomicAdd(&cur[d], 1);
    edge_src[pos] = src[e];
  }
}

struct PArgs {
  u16* hb0; u16* hb1; float* y_out;
  const int* row_start; const int* edge_src;
  const float* w_gat; const float* a_l; const float* a_r;
  const float* inputs; const float* w_in; const float* b_in;
  const float* w_W; const float* b_W; const float* w_U; const float* b_U;
  int* bar;
};

// ~55 KB LDS -> exactly 2 blocks/CU (160/55 = 2); 32 waves/CU restores wave
// diversity that the single barrier-lockstepped block lacked (Occupancy 48%).
__global__ void __launch_bounds__(PTHREADS, 8) persist(PArgs p)
{
  __shared__ __align__(16) u16 WbT[128*WSTRIDE];    // 34.8 KB: w_gat^T fp16 arena
  __shared__ __align__(16) u16 yt_bf[RPB*WSTRIDE];  // 4.35 KB: y (fp16)
  __shared__ __align__(16) u16 ht_bf[RPB*WSTRIDE];  // 4.35 KB: h (fp16)
  __shared__ float zt[RPB*HID];                     // 8 KB: fp32 GRU/LN staging
  __shared__ int   esrc_l[ECAP];                    // 3 KB
  __shared__ int   eoff[RPB+1];
  __shared__ int   degs_s[RPB];
  __shared__ float er_l[RPB*NHEAD];                 // 0.5 KB; total ~55 KB
  __shared__ int   use_l2_s;
  u16* const Wg = WbT;                              // GRU fp16 overlay (32 KB)

  const int tid  = threadIdx.x;
  const int bat   = blockIdx.x & 7;            // batch index (XCD heuristic)
  const int slot  = blockIdx.x >> 3;           // 0..63
  const int row0  = bat * NNODE + slot * RPB;
  int nr = NNODE - slot*RPB;
  const int nrows = nr < 0 ? 0 : (nr > RPB ? RPB : nr);      // 0, 8, or 16
  int* const bar_b = p.bar + bat * BARSTRIDE;
  // layout A (gather): 16 feature lanes x 4 edge-segments x 16 rows
  const int tA = tid & 15, seg = (tid >> 4) & 3, rA = tid >> 6;
  const bool actA = rA < nrows;
  const int nA     = slot*RPB + rA;
  const int nAs    = actA ? nA : 0;
  const int sbase  = bat * NNODE;
  const int hd   = tA >> 1;
  const int off8 = tA * 8;
  // layout F (epilogue/LN): 32 col-groups x 32 row-slots (upper 16 duplicate)
  const int fg = tid & 31, rs = tid >> 5, rsF = rs & (RPB-1);
  const bool actF = rs < nrows;
  const int rowF = row0 + rs;
  const int hd2 = fg >> 2, db = (fg & 3) * 4;
  // MFMA ids: waves 0-7 = 8 N-tiles (single 16-row M tile); waves 8-15 idle
  const int wv = tid >> 6, lane = tid & 63, quad = lane >> 4, lc = lane & 15;

  // ---- one-time: per-block edge cache ----
  int s0r = 0, degr = 0;
  if (actA){ s0r = p.row_start[nA]; degr = p.row_start[nA+1] - s0r; }
  if ((tid & 63) == 0) degs_s[rA] = degr;
  __syncthreads();
  if (tid == 0){
    int o = 0;
    #pragma unroll
    for (int r = 0; r < RPB; ++r){ eoff[r] = o; o += degs_s[r]; }
    eoff[RPB] = o;
  }
  __syncthreads();
  const int* eptr;
  if (eoff[RPB] <= ECAP){
    const int eb = eoff[rA];
    for (int e = tA + 16*seg; e < degr; e += 64) esrc_l[eb + e] = p.edge_src[s0r + e];
    eptr = esrc_l + eb;
  } else {
    eptr = p.edge_src + s0r;   // statistically never; correctness fallback
  }

  // ---- one-time: per-thread constants ----
  float ar4[4], al4[4];
  #pragma unroll
  for (int i=0;i<4;++i){
    ar4[i] = p.a_r[hd2*DHEAD + db + i];
    al4[i] = p.a_l[hd2*DHEAD + db + i];
  }

  load_WT_f16(WbT, p.w_gat, tid);

  // ---- init: y0 = inputs[:,0]@w_in + b_in ----
  float yb8[8], ya8[8];
  {
    const float x0 = p.inputs[((bat*SEQL + 0)*NNODE + nAs)*2 + 0];
    const float x1 = p.inputs[((bat*SEQL + 0)*NNODE + nAs)*2 + 1];
    #pragma unroll
    for (int i=0;i<8;++i){
      int f = off8 + i;
      yb8[i] = x0*p.w_in[f] + x1*p.w_in[HID+f] + p.b_in[f];
    }
    if (seg == 0) pack_y(yt_bf, rA, off8, yb8);
  }
  __syncthreads();     // yt_bf, WbT, esrc_l staged
  // initial h store goes agent-scope (path not decided yet; safe either way)
  h_stage(yt_bf, ht_bf, WbT, wv, quad, lc, fg, rs, rsF, rowF, actF, false,
          p.hb0, er_l, ar4, al4);

  // ---- XCD-locality detection + 512-wide startup barrier ----
  if (tid == 0){
    int xcc = (int)(__builtin_amdgcn_s_getreg(HWREG_XCC_ID) & 0xf);
    __hip_atomic_fetch_or(reinterpret_cast<u32*>(bar_b + OFF_MASK), 1u<<xcc,
                          __ATOMIC_RELAXED, __HIP_MEMORY_SCOPE_AGENT);
    __hip_atomic_fetch_or(reinterpret_cast<u32*>(p.bar + OFF_GMASK), 1u<<xcc,
                          __ATOMIC_RELAXED, __HIP_MEMORY_SCOPE_AGENT);
  }
  startup_bar(p.bar + OFF_GCNT);    // also publishes hb0 + masks everywhere
  if (tid == 0){
    u32 mb = __hip_atomic_load(reinterpret_cast<u32*>(bar_b + OFF_MASK),
                               __ATOMIC_RELAXED, __HIP_MEMORY_SCOPE_AGENT);
    u32 mg = __hip_atomic_load(reinterpret_cast<u32*>(p.bar + OFF_GMASK),
                               __ATOMIC_RELAXED, __HIP_MEMORY_SCOPE_AGENT);
    use_l2_s = (__popc(mb) == 1 && __popc(mg) == 8) ? 1 : 0;
  }
  __syncthreads();
  const bool use_l2 = use_l2_s != 0;

  int step = 1;

  // per-segment edge range (contiguous quarters)
  const int e_lo = (seg * degr) >> 2;
  const int e_hi = ((seg + 1) * degr) >> 2;

  int rd = 0;
  for (int idx = 0; idx < SEQL; ++idx){
    for (int st = 0; st < 4; ++st){
      for (int j = 1; j <= 4; ++j){
        const u16* __restrict__ h_rd = rd ? p.hb1 : p.hb0;
        u16* __restrict__ h_wr       = rd ? p.hb0 : p.hb1;

        // ---- gather: softmax aggregation; el/er precomputed in h_stage ----
        float acc[8] = {0.f,0.f,0.f,0.f,0.f,0.f,0.f,0.f};
        float sum = 0.f;
        {
          const float erh = er_l[rA*NHEAD + hd];
          if (use_l2){
            inv_l1();          // clear stale h lines; L2 is current (L1 is WT)
            gather_f<true >(h_rd, eptr, e_lo, e_hi, sbase, off8, hd, erh, acc, sum);
          } else {
            gather_f<false>(h_rd, eptr, e_lo, e_hi, sbase, off8, hd, erh, acc, sum);
          }
        }
        sum += __shfl_xor(sum, 16);
        sum += __shfl_xor(sum, 32);
        #pragma unroll
        for (int i=0;i<8;++i){
          acc[i] += __shfl_xor(acc[i], 16);
          acc[i] += __shfl_xor(acc[i], 32);
        }
        const float inv = 1.f / (sum + 1e-16f);
        #pragma unroll
        for (int i=0;i<8;++i) acc[i] *= inv;

        // ---- RK4 register update ----
        const bool is5 = (st == 3) && (j == 4);
        float nxt[8];
        if (j == 1){
          #pragma unroll
          for (int i=0;i<8;++i){ ya8[i] = fmaf(DT/6.f, acc[i], yb8[i]);
                                 nxt[i] = fmaf(0.5f*DT, acc[i], yb8[i]); }
        } else if (j == 2){
          #pragma unroll
          for (int i=0;i<8;++i){ ya8[i] = fmaf(DT/3.f, acc[i], ya8[i]);
                                 nxt[i] = fmaf(0.5f*DT, acc[i], yb8[i]); }
        } else if (j == 3){
          #pragma unroll
          for (int i=0;i<8;++i){ ya8[i] = fmaf(DT/3.f, acc[i], ya8[i]);
                                 nxt[i] = fmaf(DT, acc[i], yb8[i]); }
        } else {
          #pragma unroll
          for (int i=0;i<8;++i) nxt[i] = fmaf(DT/6.f, acc[i], ya8[i]);
          if (!is5){
            #pragma unroll
            for (int i=0;i<8;++i) yb8[i] = nxt[i];
          }
        }

        if (!is5){
          if (seg == 0) pack_y(yt_bf, rA, off8, nxt);
          __syncthreads();
          h_stage(yt_bf, ht_bf, WbT, wv, quad, lc, fg, rs, rsF, rowF, actF, use_l2,
                  h_wr, er_l, ar4, al4);
          grid_bar2(bar_b, NBLK_B * step, use_l2); ++step;
          rd ^= 1;
          continue;
        }

        // ---- end of interval: GRU (fp16 W in LDS) / LN / state handoff ----
        const bool last = (idx == SEQL-1);
        if (seg == 0){
          *reinterpret_cast<float4*>(zt + rA*HID + off8)     = make_float4(nxt[0],nxt[1],nxt[2],nxt[3]);
          *reinterpret_cast<float4*>(zt + rA*HID + off8 + 4) = make_float4(nxt[4],nxt[5],nxt[6],nxt[7]);
        }
        float z4[4];
        if (idx > 0){
          load_W_f16(Wg, p.w_W, tid);            // overlays WbT (restored below)
          __syncthreads();                       // zt(y_new) + w_W ready
          gemm128_1h(Wg, zt, fg, rsF, z4);       // z = y_new @ w_W
          __syncthreads();                       // gemm reads done
          {
            const float x0 = p.inputs[((bat*SEQL + idx)*NNODE + nAs)*2 + 0];
            const float x1 = p.inputs[((bat*SEQL + idx)*NNODE + nAs)*2 + 1];
            if (seg == 0){
              float hv[8];
              #pragma unroll
              for (int i=0;i<8;++i){
                int f = off8 + i;
                hv[i] = x0*p.w_in[f] + x1*p.w_in[HID+f] + p.b_in[f];
              }
              *reinterpret_cast<float4*>(zt + rA*HID + off8)     = make_float4(hv[0],hv[1],hv[2],hv[3]);
              *reinterpret_cast<float4*>(zt + rA*HID + off8 + 4) = make_float4(hv[4],hv[5],hv[6],hv[7]);
            }
          }
          load_W_f16(Wg, p.w_U, tid);
          __syncthreads();
          float u4[4];
          gemm128_1h(Wg, zt, fg, rsF, u4);       // u = h_in @ w_U
          #pragma unroll
          for (int i=0;i<4;++i)
            z4[i] = tanhf(z4[i] + u4[i] + p.b_W[fg*4+i] + p.b_U[fg*4+i]);
        } else {
          __syncthreads();                       // zt(y_new) visible in F layout
          #pragma unroll
          for (int i=0;i<4;++i) z4[i] = zt[rsF*HID + fg*4 + i];
        }
        // LayerNorm over 128 features (32 fg lanes)
        {
          float sv=0.f, qv=0.f;
          #pragma unroll
          for (int i=0;i<4;++i){ sv+=z4[i]; qv+=z4[i]*z4[i]; }
          #pragma unroll
          for (int off=1; off<32; off<<=1){
            sv += __shfl_xor(sv, off); qv += __shfl_xor(qv, off);
          }
          float mu = sv*(1.f/HID);
          float r  = rsqrtf(qv*(1.f/HID) - mu*mu + 1e-5f);
          #pragma unroll
          for (int i=0;i<4;++i) z4[i] = (z4[i]-mu)*r;
        }
        __syncthreads();                         // all zt readers done
        if (rs < RPB)
          *reinterpret_cast<float4*>(zt + rs*HID + fg*4) = make_float4(z4[0],z4[1],z4[2],z4[3]);
        if (last){
          if (actF)
            *reinterpret_cast<float4*>(p.y_out + (size_t)rowF*HID + fg*4) =
                make_float4(z4[0],z4[1],z4[2],z4[3]);
          // final stage: no more barriers; blocks exit uniformly
        } else {
          __syncthreads();                       // zt(z) visible
          if (idx > 0) load_WT_f16(WbT, p.w_gat, tid);  // restore w_gat^T fp16
          #pragma unroll
          for (int i=0;i<8;++i) yb8[i] = zt[rA*HID + off8 + i];  // new y state
          if (seg == 0) pack_y(yt_bf, rA, off8, yb8);
          __syncthreads();
          h_stage(yt_bf, ht_bf, WbT, wv, quad, lc, fg, rs, rsF, rowF, actF, use_l2,
                  h_wr, er_l, ar4, al4);
          grid_bar2(bar_b, NBLK_B * step, use_l2); ++step;
          rd ^= 1;
        }
      }
    }
  }
}

// out = tanh(ret @ w_o1 + b_o1) @ w_o2 + b_o2, fp32 output
__global__ void __launch_bounds__(256, 2) out_kernel(
    const float* __restrict__ y_base,
    const float* __restrict__ w_o1, const float* __restrict__ b_o1,
    const float* __restrict__ w_o2, const float* __restrict__ b_o2,
    float* __restrict__ out)
{
  __shared__ float Wl[HID*HID];
  __shared__ float yt[ORPB*HID];
  const int tid = threadIdx.x;
  const int row0 = blockIdx.x * ORPB;
  const int rA = tid >> 4, tA = tid & 15;
  const int rowA = row0 + rA;
  {
    float4 v0 = *reinterpret_cast<const float4*>(y_base + rowA*HID + tA*8);
    float4 v1 = *reinterpret_cast<const float4*>(y_base + rowA*HID + tA*8 + 4);
    *reinterpret_cast<float4*>(yt + rA*HID + tA*8)     = v0;
    *reinterpret_cast<float4*>(yt + rA*HID + tA*8 + 4) = v1;
  }
  load_W<256>(Wl, w_o1, tid);
  __syncthreads();
  const int fg = tid & 31, rs = tid >> 5;
  float t0[4], t1[4];
  gemm128<8>(Wl, yt, fg, rs, t0, t1);
  #pragma unroll
  for (int i=0;i<4;++i){
    float bb = b_o1[fg*4+i];
    t0[i] = tanhf(t0[i] + bb);
    t1[i] = tanhf(t1[i] + bb);
  }
  __syncthreads();
  *reinterpret_cast<float4*>(yt + rs*HID + fg*4)     = make_float4(t0[0],t0[1],t0[2],t0[3]);
  *reinterpret_cast<float4*>(yt + (rs+8)*HID + fg*4) = make_float4(t1[0],t1[1],t1[2],t1[3]);
  load_W<256>(Wl, w_o2, tid);
  __syncthreads();
  float o0[4], o1[4];
  gemm128<8>(Wl, yt, fg, rs, o0, o1);
  const int rowF0 = row0 + rs, rowF1 = row0 + rs + 8;
  *reinterpret_cast<float4*>(out + rowF0*HID + fg*4) =
      make_float4(o0[0]+b_o2[fg*4+0], o0[1]+b_o2[fg*4+1], o0[2]+b_o2[fg*4+2], o0[3]+b_o2[fg*4+3]);
  *reinterpret_cast<float4*>(out + rowF1*HID + fg*4) =
      make_float4(o1[0]+b_o2[fg*4+0], o1[1]+b_o2[fg*4+1], o1[2]+b_o2[fg*4+2], o1[3]+b_o2[fg*4+3]);
}

extern "C" void kernel_launch(void* const* d_in, const int* in_sizes, int n_in,
                              void* d_out, int out_size, void* d_ws, size_t ws_size,
                              hipStream_t stream)
{
  const float* inputs = (const float*)d_in[0];
  const int* src      = (const int*)d_in[1];
  const int* dst      = (const int*)d_in[2];
  const float* w_in   = (const float*)d_in[3];
  const float* b_in   = (const float*)d_in[4];
  const float* w_gat  = (const float*)d_in[5];
  const float* a_l    = (const float*)d_in[6];
  const float* a_r    = (const float*)d_in[7];
  const float* w_W    = (const float*)d_in[8];
  const float* b_W    = (const float*)d_in[9];
  const float* w_U    = (const float*)d_in[10];
  const float* b_U    = (const float*)d_in[11];
  const float* w_o1   = (const float*)d_in[12];
  const float* b_o1   = (const float*)d_in[13];
  const float* w_o2   = (const float*)d_in[14];
  const float* b_o2   = (const float*)d_in[15];

  const size_t RH  = (size_t)NROWS * HID;     // 1,024,000 (y_out floats)
  const size_t RH2 = (size_t)NROWS * HSTR;    // 1,152,000 (u16 per exchange buf)
  float* y_out = reinterpret_cast<float*>(d_ws);
  u16*   hbuf  = reinterpret_cast<u16*>(y_out + RH);
  u16*   hb0   = hbuf;
  u16*   hb1   = hbuf + RH2;
  int*   I     = reinterpret_cast<int*>(hbuf + 2*RH2);
  int* row_start = I;
  int* edge_src  = I + 1024;
  int* bar       = I + 1024 + NEDGE;

  size_t need = RH*sizeof(float) + 2*RH2*sizeof(u16)
              + (size_t)(1024 + NEDGE + NBATCH*BARSTRIDE)*sizeof(int);
  if (ws_size < need) return;

  csr_kernel<<<1, 1024, 0, stream>>>(src, dst, row_start, edge_src, bar);

  PArgs pa;
  pa.hb0 = hb0; pa.hb1 = hb1; pa.y_out = y_out;
  pa.row_start = row_start; pa.edge_src = edge_src;
  pa.w_gat = w_gat; pa.a_l = a_l; pa.a_r = a_r;
  pa.inputs = inputs; pa.w_in = w_in; pa.b_in = b_in;
  pa.w_W = w_W; pa.b_W = b_W; pa.w_U = w_U; pa.b_U = b_U;
  pa.bar = bar;

  persist<<<NBLK_P, PTHREADS, 0, stream>>>(pa);

  out_kernel<<<NBLK_O, 256, 0, stream>>>(y_out, w_o1, b_o1, w_o2, b_o2, (float*)d_out);
}

// Round 12
// 1724.627 us; speedup vs baseline: 3.5373x; 3.5373x over previous
//
#include <hip/hip_runtime.h>

#define NNODE 1000
#define NBATCH 8
#define SEQL 12
#define NHEAD 8
#define DHEAD 16
#define HID 128
#define NEDGE 16000
#define NROWS (NBATCH*NNODE)   // 8000
#define RPB 32                 // rows per persistent block
#define NBLK_P 256             // 8 batch-groups x 32 slots; 1 block/CU
#define NBLK_B 32              // blocks per batch = barrier width
#define BARSTRIDE 64           // ints between per-batch counters (256 B)
#define PTHREADS 1024
#define ORPB 16
#define NBLK_O (NROWS/ORPB)    // 500
#define DT 0.25f
#define ECAP 768               // LDS edge cache (block mean 512)
#define SPIN_LIMIT 2000000ULL  // 20 ms: transient slowness costs time, not NaN (R6)
#define WSTRIDE 136            // padded K-stride (u16, LDS tiles)
#define WLO (128*WSTRIDE)      // u16 offset of the lo-residual matrix
#define HSTR 144               // exchange row stride (u16): 128 bf16 h + 8 f32 el

// bar[] layout (ints), all zeroed by csr_kernel:
//   bat*64 + 0  : per-batch round counter
//   bat*64 + 32 : per-batch XCD mask
//   48          : global XCD mask   (batch0 stride area, unused offsets)
//   56          : startup barrier counter (256-wide)
#define OFF_MASK  32
#define OFF_GMASK 48
#define OFF_GCNT  56
#define HWREG_XCC_ID 6164      // s_getreg imm: id=20 (XCC_ID), offset=0, size=4

// Journal (final):
// R1  (L2-local exchange, asm poll bug): 189ms. Fixed in R2.
// R2  (XCD-L2 exchange + CAS-poll barrier): 2746 -> 1874 us. KEPT.
// R3  (edge-balanced LDS-atomic gather): 10x regression. REVERTED.
// R4/R6/R9 (deepen gather pipeline x3): all blocked by the 64-VGPR allocation
//    (spill -> HBM blowup / NaN / +200us). Lever DEAD.
// R5  (el precomputed in h_stage, exchanged with h): 1874 -> 1744. KEPT.
// R7  (ht_bf split + MFMA 2-chain): -> 1733. KEPT.
// R8  (plain loads + per-round buffer_inv; L1 is WT so inv restores
//     coherence): 1731, WRITE 335->214 MB. KEPT — BEST VERIFIED STATE.
// R10/R11 (fp16 + 2 blocks/CU): launch_bounds 2nd arg = min waves/EU.
//    (1024,8) forces 2 blocks/CU but squeezes to 32 VGPR -> spills (6100us);
//    (1024,4) allows >64 VGPR -> 1 block/CU -> 512-block grid can't co-reside
//    -> barrier breaks -> absmax 1.6. Occupancy lever DEAD (gather needs ~90
//    regs; 2-block residency needs <=64). R12: R8 restored verbatim.
//
// Structural plateau analysis: 192 serial h-exchange rounds (RK4 x SEQL) x
// ~9us/round = {gather L2-latency chain + MFMA h-stage + 32-block barrier}.
// Remaining stall is sync-latency of the barrier-lockstepped persistent loop;
// not movable within the 64-VGPR / 1-block-CU envelope this problem pins.

typedef unsigned short u16;
typedef unsigned int   u32;
typedef unsigned long long u64;
typedef __attribute__((ext_vector_type(8))) short bf16x8;
typedef __attribute__((ext_vector_type(4))) float f32x4;
typedef __attribute__((ext_vector_type(4))) unsigned int u32x4;

__device__ __forceinline__ u16 f2bf(float f){
  u32 x = __float_as_uint(f);
  return (u16)((x + 0x7fffu + ((x>>16)&1u)) >> 16);
}
__device__ __forceinline__ float bf2f(u16 u){ return __uint_as_float(((u32)u)<<16); }

// ---- exchange primitives ----
// Agent path (MALL point-of-coherence): correct under ANY block->XCD mapping.
__device__ __forceinline__ u64 ld_agent_u64(const u16* p){
  return __hip_atomic_load(reinterpret_cast<const u64*>(p),
                           __ATOMIC_RELAXED, __HIP_MEMORY_SCOPE_AGENT);
}
__device__ __forceinline__ void st_agent_u64(u16* p, u64 v){
  __hip_atomic_store(reinterpret_cast<u64*>(p), v,
                     __ATOMIC_RELAXED, __HIP_MEMORY_SCOPE_AGENT);
}
__device__ __forceinline__ float ld_agent_f32(const float* p){
  u32 v = __hip_atomic_load(reinterpret_cast<const u32*>(p),
                            __ATOMIC_RELAXED, __HIP_MEMORY_SCOPE_AGENT);
  return __uint_as_float(v);
}
__device__ __forceinline__ void st_agent_f32(float* p, float v){
  __hip_atomic_store(reinterpret_cast<u32*>(p), __float_as_uint(v),
                     __ATOMIC_RELAXED, __HIP_MEMORY_SCOPE_AGENT);
}

// L1 invalidate (gfx940+): after the per-round barrier, clears stale h lines
// in THIS CU's vector L1; plain loads then read current L2 (L1 is WT). R8-proven.
__device__ __forceinline__ void inv_l1(){
  asm volatile("buffer_inv sc0\n\ts_waitcnt vmcnt(0)" ::: "memory");
}

// L2-barrier poll: failing CAS executed at the XCD TCC atomic unit returns the
// current counter value — meets the fetch_add increments at the same unit.
__device__ __forceinline__ int poll_l2(int* p){
  int exp = -1;                     // counter is never -1
  __hip_atomic_compare_exchange_strong(p, &exp, -1,
      __ATOMIC_RELAXED, __ATOMIC_RELAXED, __HIP_MEMORY_SCOPE_WORKGROUP);
  return exp;
}

// ---- barriers ----
__device__ __forceinline__ void grid_bar2(int* bar, int target, bool l2){
  __syncthreads();   // drains each wave's stores (vmcnt 0) before arrival
  if (threadIdx.x == 0){
    unsigned long long t0;
    if (l2){
      __hip_atomic_fetch_add(bar, 1, __ATOMIC_RELAXED, __HIP_MEMORY_SCOPE_WORKGROUP);
      t0 = __builtin_amdgcn_s_memrealtime();
      while (poll_l2(bar) < target){
        __builtin_amdgcn_s_sleep(2);
        if (__builtin_amdgcn_s_memrealtime() - t0 > SPIN_LIMIT) break;
      }
    } else {
      __hip_atomic_fetch_add(bar, 1, __ATOMIC_RELEASE, __HIP_MEMORY_SCOPE_AGENT);
      t0 = __builtin_amdgcn_s_memrealtime();
      while (__hip_atomic_load(bar, __ATOMIC_RELAXED, __HIP_MEMORY_SCOPE_AGENT) < target){
        __builtin_amdgcn_s_sleep(2);
        if (__builtin_amdgcn_s_memrealtime() - t0 > SPIN_LIMIT) break;
      }
    }
  }
  __syncthreads();
}

// one-time 256-block agent barrier (orders initial h stores + XCD-mask ORs)
__device__ __forceinline__ void startup_bar(int* cnt){
  __syncthreads();
  if (threadIdx.x == 0){
    __hip_atomic_fetch_add(cnt, 1, __ATOMIC_RELEASE, __HIP_MEMORY_SCOPE_AGENT);
    unsigned long long t0 = __builtin_amdgcn_s_memrealtime();
    while (__hip_atomic_load(cnt, __ATOMIC_RELAXED, __HIP_MEMORY_SCOPE_AGENT) < NBLK_P){
      __builtin_amdgcn_s_sleep(2);
      if (__builtin_amdgcn_s_memrealtime() - t0 > SPIN_LIMIT) break;
    }
  }
  __syncthreads();
}

// copy a 128x128 fp32 matrix global->LDS, NT threads (GRU + out_kernel path)
template<int NT>
__device__ __forceinline__ void load_W(float* Wl, const float* g, int tid){
  #pragma unroll
  for (int c = 0; c < (HID*HID/4)/NT; ++c){
    int e = (c*NT + tid)*4;
    *reinterpret_cast<float4*>(Wl + e) = *reinterpret_cast<const float4*>(g + e);
  }
}

// split-precision transposed load: W[k][n] fp32 -> WbT[n][k] hi/lo bf16
__device__ __forceinline__ void load_WT_split(u16* WbT, const float* g, int tid){
  #pragma unroll
  for (int c = 0; c < 16; ++c){
    int flat = c*PTHREADS + tid;        // = k*128 + n
    int k = flat >> 7, n = flat & 127;
    float v = g[flat];
    u16 hi = f2bf(v);
    u16 lo = f2bf(v - bf2f(hi));
    WbT[n*WSTRIDE + k]       = hi;
    WbT[WLO + n*WSTRIDE + k] = lo;
  }
}

// one row, 4 cols: o[j] = sum_k yt[rs][k]*Wl[k][fg*4+j]  (fp32, GRU path)
__device__ __forceinline__ void gemm128_1(const float* Wl, const float* yt, int fg, int rs,
                                          float o[4]){
  float a0[4]={0.f,0.f,0.f,0.f};
  #pragma unroll 4
  for (int k=0;k<HID;k+=4){
    float4 ya = *reinterpret_cast<const float4*>(yt + rs*HID + k);
    #pragma unroll
    for (int kk=0;kk<4;++kk){
      const float* wr = Wl + (k+kk)*HID + fg*4;
      float av = (&ya.x)[kk];
      #pragma unroll
      for (int i=0;i<4;++i) a0[i] = fmaf(wr[i], av, a0[i]);
    }
  }
  #pragma unroll
  for (int i=0;i<4;++i) o[i]=a0[i];
}

// two rows (rs, rs+RSTEP), 4 cols — used by out_kernel
template<int RSTEP>
__device__ __forceinline__ void gemm128(const float* Wl, const float* yt, int fg, int rs,
                                        float o0[4], float o1[4]){
  float a0[4]={0.f,0.f,0.f,0.f}, a1[4]={0.f,0.f,0.f,0.f};
  #pragma unroll 4
  for (int k=0;k<HID;k+=4){
    float4 ya = *reinterpret_cast<const float4*>(yt + rs*HID + k);
    float4 yb = *reinterpret_cast<const float4*>(yt + (rs+RSTEP)*HID + k);
    #pragma unroll
    for (int kk=0;kk<4;++kk){
      const float* wr = Wl + (k+kk)*HID + fg*4;
      float av = (&ya.x)[kk];
      float bv = (&yb.x)[kk];
      #pragma unroll
      for (int i=0;i<4;++i){
        float w = wr[i];
        a0[i] = fmaf(w, av, a0[i]);
        a1[i] = fmaf(w, bv, a1[i]);
      }
    }
  }
  #pragma unroll
  for (int i=0;i<4;++i){ o0[i]=a0[i]; o1[i]=a1[i]; }
}

// pack 8 fp32 -> 8 bf16 into yt_bf[rA][off8..off8+7]
__device__ __forceinline__ void pack_y(u16* yt_bf, int rA, int off8, const float y[8]){
  uint4 w;
  w.x = (u32)f2bf(y[0]) | ((u32)f2bf(y[1])<<16);
  w.y = (u32)f2bf(y[2]) | ((u32)f2bf(y[3])<<16);
  w.z = (u32)f2bf(y[4]) | ((u32)f2bf(y[5])<<16);
  w.w = (u32)f2bf(y[6]) | ((u32)f2bf(y[7])<<16);
  *reinterpret_cast<uint4*>(yt_bf + rA*WSTRIDE + off8) = w;
}

// per-edge decode + attention + register accumulate. el precomputed (h_stage),
// so the weight is a short chain: add -> leaky -> exp. No cross-lane ops.
__device__ __forceinline__ void edge_acc(const u32x4 q, float el, float erh,
                                         float acc[8], float& sum){
  float hv[8];
  hv[0]=__uint_as_float(q[0]<<16); hv[1]=__uint_as_float(q[0]&0xffff0000u);
  hv[2]=__uint_as_float(q[1]<<16); hv[3]=__uint_as_float(q[1]&0xffff0000u);
  hv[4]=__uint_as_float(q[2]<<16); hv[5]=__uint_as_float(q[2]&0xffff0000u);
  hv[6]=__uint_as_float(q[3]<<16); hv[7]=__uint_as_float(q[3]&0xffff0000u);
  const float x = el + erh;
  const float w = __expf(fminf(fmaxf(x, 0.2f*x), 30.f));
  sum += w;
  #pragma unroll
  for (int i=0;i<8;++i) acc[i] = fmaf(w, hv[i], acc[i]);
}

// gather: softmax-weighted aggregation over this thread's edge range.
// L2=true : PLAIN loads (L1-cached; coherent because L1 was invalidated this
//           round and CDNA L1 is write-through). 4-edge blocks; the compiler
//           tracks load->use deps and software-pipelines within 64 VGPRs.
// L2=false: agent-scope fallback (correctness under any XCD mapping).
template<bool L2>
__device__ __forceinline__ void gather_f(const u16* __restrict__ h_rd,
    const int* __restrict__ eptr, int e_lo, int e_hi, int sbase, int off8, int hd,
    float erh, float acc[8], float& sum)
{
  if constexpr (L2){
    int e = e_lo;
    for (; e + 4 <= e_hi; e += 4){
      const u16* r0 = h_rd + (size_t)(sbase + eptr[e+0])*HSTR;
      const u16* r1 = h_rd + (size_t)(sbase + eptr[e+1])*HSTR;
      const u16* r2 = h_rd + (size_t)(sbase + eptr[e+2])*HSTR;
      const u16* r3 = h_rd + (size_t)(sbase + eptr[e+3])*HSTR;
      u32x4 q0 = *reinterpret_cast<const u32x4*>(r0 + off8);
      u32x4 q1 = *reinterpret_cast<const u32x4*>(r1 + off8);
      u32x4 q2 = *reinterpret_cast<const u32x4*>(r2 + off8);
      u32x4 q3 = *reinterpret_cast<const u32x4*>(r3 + off8);
      float x0 = reinterpret_cast<const float*>(r0 + 128)[hd];
      float x1 = reinterpret_cast<const float*>(r1 + 128)[hd];
      float x2 = reinterpret_cast<const float*>(r2 + 128)[hd];
      float x3 = reinterpret_cast<const float*>(r3 + 128)[hd];
      edge_acc(q0, x0, erh, acc, sum);
      edge_acc(q1, x1, erh, acc, sum);
      edge_acc(q2, x2, erh, acc, sum);
      edge_acc(q3, x3, erh, acc, sum);
    }
    for (; e < e_hi; ++e){
      const u16* r = h_rd + (size_t)(sbase + eptr[e])*HSTR;
      u32x4 q = *reinterpret_cast<const u32x4*>(r + off8);
      float x = reinterpret_cast<const float*>(r + 128)[hd];
      edge_acc(q, x, erh, acc, sum);
    }
  } else {
    for (int e = e_lo; e < e_hi; ++e){
      const u16* r = h_rd + (size_t)(sbase + eptr[e])*HSTR;
      const u64 L = ld_agent_u64(r + off8);
      const u64 H = ld_agent_u64(r + off8 + 4);
      const float x = ld_agent_f32(reinterpret_cast<const float*>(r + 128) + hd);
      u32x4 v;
      v[0]=(u32)L; v[1]=(u32)(L>>32); v[2]=(u32)H; v[3]=(u32)(H>>32);
      edge_acc(v, x, erh, acc, sum);
    }
  }
}

// MFMA h-stage: yt_bf holds y (bf16, read-only here); h goes to ht_bf
// (separate buffer -> one fewer sync: no WAR on yt_bf). Two accumulator
// chains halve dependent-MFMA latency. Wire-stores packed u64 h + fp32 el.
__device__ __forceinline__ void h_stage(const u16* yt_bf, u16* ht_bf, const u16* WbT,
    int mt, int nt, int quad, int lc,
    int fg, int rs, int rowF, bool actF, bool l2,
    u16* __restrict__ h_wr, float* er_l, const float ar4[4], const float al4[4])
{
  f32x4 c0 = {0.f,0.f,0.f,0.f}, c1 = {0.f,0.f,0.f,0.f};
  const u16* arow = yt_bf + (mt*16 + lc)*WSTRIDE;
  const u16* brow = WbT  + (nt*16 + lc)*WSTRIDE;
  #pragma unroll
  for (int k0 = 0; k0 < 4; ++k0){
    const int off = k0*32 + quad*8;
    bf16x8 a  = *reinterpret_cast<const bf16x8*>(arow + off);
    bf16x8 bh = *reinterpret_cast<const bf16x8*>(brow + off);
    bf16x8 bl = *reinterpret_cast<const bf16x8*>(brow + WLO + off);
    if (k0 & 1){
      c1 = __builtin_amdgcn_mfma_f32_16x16x32_bf16(a, bh, c1, 0, 0, 0);
      c1 = __builtin_amdgcn_mfma_f32_16x16x32_bf16(a, bl, c1, 0, 0, 0);
    } else {
      c0 = __builtin_amdgcn_mfma_f32_16x16x32_bf16(a, bh, c0, 0, 0, 0);
      c0 = __builtin_amdgcn_mfma_f32_16x16x32_bf16(a, bl, c0, 0, 0, 0);
    }
  }
  {
    const int col = nt*16 + lc;
    #pragma unroll
    for (int r = 0; r < 4; ++r)
      ht_bf[(mt*16 + quad*4 + r)*WSTRIDE + col] = f2bf(c0[r] + c1[r]);
  }
  __syncthreads();              // h bf16 visible block-wide
  const u64 pk = *reinterpret_cast<const u64*>(ht_bf + rs*WSTRIDE + fg*4);
  if (actF){
    if (l2) *reinterpret_cast<u64*>(h_wr + (size_t)rowF*HSTR + fg*4) = pk;
    else    st_agent_u64(h_wr + (size_t)rowF*HSTR + fg*4, pk);
  }
  const float h0 = bf2f((u16)pk),       h1 = bf2f((u16)(pk>>16));
  const float h2 = bf2f((u16)(pk>>32)), h3 = bf2f((u16)(pk>>48));
  float er = 0.f, el = 0.f;
  er = fmaf(h0, ar4[0], er); er = fmaf(h1, ar4[1], er);
  er = fmaf(h2, ar4[2], er); er = fmaf(h3, ar4[3], er);
  el = fmaf(h0, al4[0], el); el = fmaf(h1, al4[1], el);
  el = fmaf(h2, al4[2], el); el = fmaf(h3, al4[3], el);
  er += __shfl_xor(er,1); er += __shfl_xor(er,2);
  el += __shfl_xor(el,1); el += __shfl_xor(el,2);
  if ((fg & 3) == 0 && actF){
    er_l[rs*NHEAD + (fg>>2)] = er;
    float* elp = reinterpret_cast<float*>(h_wr + (size_t)rowF*HSTR + 128);
    if (l2) elp[fg>>2] = el;
    else    st_agent_f32(elp + (fg>>2), el);
  }
}

// Build CSR (edges sorted by dst); zero the per-batch barrier area.
__global__ void csr_kernel(const int* __restrict__ src, const int* __restrict__ dst,
                           int* __restrict__ row_start, int* __restrict__ edge_src,
                           int* __restrict__ bar){
  __shared__ int cnt[1024];
  __shared__ int scanb[1024];
  __shared__ int cur[1024];
  int tid = threadIdx.x;
  if (tid < NBATCH*BARSTRIDE) bar[tid] = 0;
  cnt[tid] = 0;
  __syncthreads();
  for (int e = tid; e < NEDGE; e += 1024) atomicAdd(&cnt[dst[e]], 1);
  __syncthreads();
  int v = cnt[tid];
  scanb[tid] = v;
  __syncthreads();
  for (int off=1; off<1024; off<<=1){
    int t = (tid >= off) ? scanb[tid-off] : 0;
    __syncthreads();
    scanb[tid] += t;
    __syncthreads();
  }
  int incl = scanb[tid];
  if (tid < NNODE){ cur[tid] = incl - v; row_start[tid+1] = incl; }
  if (tid == 0) row_start[0] = 0;
  __syncthreads();
  for (int e = tid; e < NEDGE; e += 1024){
    int d = dst[e];
    int pos = atomicAdd(&cur[d], 1);
    edge_src[pos] = src[e];
  }
}

struct PArgs {
  u16* hb0; u16* hb1; float* y_out;
  const int* row_start; const int* edge_src;
  const float* w_gat; const float* a_l; const float* a_r;
  const float* inputs; const float* w_in; const float* b_in;
  const float* w_W; const float* b_W; const float* w_U; const float* b_U;
  int* bar;
};

__global__ void __launch_bounds__(PTHREADS, 4) persist(PArgs p)
{
  __shared__ __align__(16) u16 WbT[2*128*WSTRIDE];  // 68 KB: w_gat^T hi/lo (bf16)
  __shared__ __align__(16) u16 yt_bf[RPB*WSTRIDE];  // 8.5 KB: y (bf16)
  __shared__ __align__(16) u16 ht_bf[RPB*WSTRIDE];  // 8.5 KB: h (bf16)
  __shared__ float zt[RPB*HID];                     // 16 KB: fp32 GRU/LN staging
  __shared__ int   esrc_l[ECAP];
  __shared__ int   eoff[RPB+1];
  __shared__ int   degs_s[RPB];
  __shared__ float er_l[RPB*NHEAD];                 // total ~106 KB -> 1 block/CU
  __shared__ int   use_l2_s;
  float* const Wlf = reinterpret_cast<float*>(WbT); // 64 KB fp32 overlay (GRU)

  const int tid  = threadIdx.x;
  const int bat   = blockIdx.x & 7;            // batch index (XCD heuristic)
  const int slot  = blockIdx.x >> 3;           // 0..31
  const int row0  = bat * NNODE + slot * RPB;
  const int nrows = (slot == 31) ? (NNODE - 31*RPB) : RPB;   // 8 or 32
  int* const bar_b = p.bar + bat * BARSTRIDE;
  // layout A (gather): 16 threads x 2 edge-segments per row, 32 rows
  const int tA = tid & 15, seg = (tid >> 4) & 1, rA = tid >> 5;
  const bool actA = rA < nrows;
  const int nA     = slot*RPB + rA;
  const int nAs    = actA ? nA : 0;
  const int sbase  = bat * NNODE;
  const int hd   = tA >> 1;
  const int off8 = tA * 8;
  // layout F (epilogue/LN): 32 col-groups (4 cols) x 32 rows
  const int fg = tid & 31, rs = tid >> 5;
  const bool actF = rs < nrows;
  const int rowF = row0 + rs;
  const int hd2 = fg >> 2, db = (fg & 3) * 4;
  // MFMA ids: 16 waves = 2 M-tiles x 8 N-tiles
  const int wv = tid >> 6, lane = tid & 63, quad = lane >> 4, lc = lane & 15;
  const int mt = wv & 1, nt = wv >> 1;

  // ---- one-time: per-block edge cache ----
  int s0r = 0, degr = 0;
  if (actA){ s0r = p.row_start[nA]; degr = p.row_start[nA+1] - s0r; }
  if ((tid & 31) == 0) degs_s[rA] = degr;
  __syncthreads();
  if (tid == 0){
    int o = 0;
    #pragma unroll
    for (int r = 0; r < RPB; ++r){ eoff[r] = o; o += degs_s[r]; }
    eoff[RPB] = o;
  }
  __syncthreads();
  const int* eptr;
  if (eoff[RPB] <= ECAP){
    const int eb = eoff[rA];
    for (int e = tA + 16*seg; e < degr; e += 32) esrc_l[eb + e] = p.edge_src[s0r + e];
    eptr = esrc_l + eb;
  } else {
    eptr = p.edge_src + s0r;   // statistically never; correctness fallback
  }

  // ---- one-time: per-thread constants ----
  float ar4[4], al4[4];
  #pragma unroll
  for (int i=0;i<4;++i){
    ar4[i] = p.a_r[hd2*DHEAD + db + i];
    al4[i] = p.a_l[hd2*DHEAD + db + i];
  }

  load_WT_split(WbT, p.w_gat, tid);

  // ---- init: y0 = inputs[:,0]@w_in + b_in ----
  float yb8[8], ya8[8];
  {
    const float x0 = p.inputs[((bat*SEQL + 0)*NNODE + nAs)*2 + 0];
    const float x1 = p.inputs[((bat*SEQL + 0)*NNODE + nAs)*2 + 1];
    #pragma unroll
    for (int i=0;i<8;++i){
      int f = off8 + i;
      yb8[i] = x0*p.w_in[f] + x1*p.w_in[HID+f] + p.b_in[f];
    }
    if (seg == 0) pack_y(yt_bf, rA, off8, yb8);
  }
  __syncthreads();     // yt_bf, WbT, esrc_l staged
  // initial h store goes agent-scope (path not decided yet; safe either way)
  h_stage(yt_bf, ht_bf, WbT, mt, nt, quad, lc, fg, rs, rowF, actF, false, p.hb0, er_l, ar4, al4);

  // ---- XCD-locality detection + 256-wide startup barrier ----
  // use_l2 requires: all 32 blocks of this batch on ONE XCD (popc==1) AND the
  // register genuinely distinguishing 8 XCDs chip-wide (popc==8) — a bogus/
  // constant hwreg read yields global popc 1 -> safe fallback to agent path.
  if (tid == 0){
    int xcc = (int)(__builtin_amdgcn_s_getreg(HWREG_XCC_ID) & 0xf);
    __hip_atomic_fetch_or(reinterpret_cast<u32*>(bar_b + OFF_MASK), 1u<<xcc,
                          __ATOMIC_RELAXED, __HIP_MEMORY_SCOPE_AGENT);
    __hip_atomic_fetch_or(reinterpret_cast<u32*>(p.bar + OFF_GMASK), 1u<<xcc,
                          __ATOMIC_RELAXED, __HIP_MEMORY_SCOPE_AGENT);
  }
  startup_bar(p.bar + OFF_GCNT);    // also publishes hb0 + masks everywhere
  if (tid == 0){
    u32 mb = __hip_atomic_load(reinterpret_cast<u32*>(bar_b + OFF_MASK),
                               __ATOMIC_RELAXED, __HIP_MEMORY_SCOPE_AGENT);
    u32 mg = __hip_atomic_load(reinterpret_cast<u32*>(p.bar + OFF_GMASK),
                               __ATOMIC_RELAXED, __HIP_MEMORY_SCOPE_AGENT);
    use_l2_s = (__popc(mb) == 1 && __popc(mg) == 8) ? 1 : 0;
  }
  __syncthreads();
  const bool use_l2 = use_l2_s != 0;

  int step = 1;

  // per-segment edge range (contiguous halves)
  const int half0 = (degr + 1) >> 1;
  const int e_lo = seg ? half0 : 0;
  const int e_hi = seg ? degr  : half0;

  int rd = 0;
  for (int idx = 0; idx < SEQL; ++idx){
    for (int st = 0; st < 4; ++st){
      for (int j = 1; j <= 4; ++j){
        const u16* __restrict__ h_rd = rd ? p.hb1 : p.hb0;
        u16* __restrict__ h_wr       = rd ? p.hb0 : p.hb1;

        // ---- gather: softmax aggregation; el/er precomputed in h_stage ----
        float acc[8] = {0.f,0.f,0.f,0.f,0.f,0.f,0.f,0.f};
        float sum = 0.f;
        {
          const float erh = er_l[rA*NHEAD + hd];
          if (use_l2){
            inv_l1();          // clear stale h lines; L2 is current (L1 is WT)
            gather_f<true >(h_rd, eptr, e_lo, e_hi, sbase, off8, hd, erh, acc, sum);
          } else {
            gather_f<false>(h_rd, eptr, e_lo, e_hi, sbase, off8, hd, erh, acc, sum);
          }
        }
        sum += __shfl_xor(sum, 16);
        #pragma unroll
        for (int i=0;i<8;++i) acc[i] += __shfl_xor(acc[i], 16);
        const float inv = 1.f / (sum + 1e-16f);
        #pragma unroll
        for (int i=0;i<8;++i) acc[i] *= inv;

        // ---- RK4 register update ----
        const bool is5 = (st == 3) && (j == 4);
        float nxt[8];
        if (j == 1){
          #pragma unroll
          for (int i=0;i<8;++i){ ya8[i] = fmaf(DT/6.f, acc[i], yb8[i]);
                                 nxt[i] = fmaf(0.5f*DT, acc[i], yb8[i]); }
        } else if (j == 2){
          #pragma unroll
          for (int i=0;i<8;++i){ ya8[i] = fmaf(DT/3.f, acc[i], ya8[i]);
                                 nxt[i] = fmaf(0.5f*DT, acc[i], yb8[i]); }
        } else if (j == 3){
          #pragma unroll
          for (int i=0;i<8;++i){ ya8[i] = fmaf(DT/3.f, acc[i], ya8[i]);
                                 nxt[i] = fmaf(DT, acc[i], yb8[i]); }
        } else {
          #pragma unroll
          for (int i=0;i<8;++i) nxt[i] = fmaf(DT/6.f, acc[i], ya8[i]);
          if (!is5){
            #pragma unroll
            for (int i=0;i<8;++i) yb8[i] = nxt[i];
          }
        }

        if (!is5){
          if (seg == 0) pack_y(yt_bf, rA, off8, nxt);
          __syncthreads();
          h_stage(yt_bf, ht_bf, WbT, mt, nt, quad, lc, fg, rs, rowF, actF, use_l2, h_wr, er_l, ar4, al4);
          grid_bar2(bar_b, NBLK_B * step, use_l2); ++step;
          rd ^= 1;
          continue;
        }

        // ---- end of interval: GRU (fp32 vector) / LN / state handoff ----
        const bool last = (idx == SEQL-1);
        if (seg == 0){
          *reinterpret_cast<float4*>(zt + rA*HID + off8)     = make_float4(nxt[0],nxt[1],nxt[2],nxt[3]);
          *reinterpret_cast<float4*>(zt + rA*HID + off8 + 4) = make_float4(nxt[4],nxt[5],nxt[6],nxt[7]);
        }
        float z4[4];
        if (idx > 0){
          load_W<PTHREADS>(Wlf, p.w_W, tid);     // overlays WbT (restored below)
          __syncthreads();                       // zt(y_new) + w_W ready
          gemm128_1(Wlf, zt, fg, rs, z4);        // z = y_new @ w_W
          __syncthreads();                       // gemm reads done
          {
            const float x0 = p.inputs[((bat*SEQL + idx)*NNODE + nAs)*2 + 0];
            const float x1 = p.inputs[((bat*SEQL + idx)*NNODE + nAs)*2 + 1];
            if (seg == 0){
              float hv[8];
              #pragma unroll
              for (int i=0;i<8;++i){
                int f = off8 + i;
                hv[i] = x0*p.w_in[f] + x1*p.w_in[HID+f] + p.b_in[f];
              }
              *reinterpret_cast<float4*>(zt + rA*HID + off8)     = make_float4(hv[0],hv[1],hv[2],hv[3]);
              *reinterpret_cast<float4*>(zt + rA*HID + off8 + 4) = make_float4(hv[4],hv[5],hv[6],hv[7]);
            }
          }
          load_W<PTHREADS>(Wlf, p.w_U, tid);
          __syncthreads();
          float u4[4];
          gemm128_1(Wlf, zt, fg, rs, u4);        // u = h_in @ w_U
          #pragma unroll
          for (int i=0;i<4;++i)
            z4[i] = tanhf(z4[i] + u4[i] + p.b_W[fg*4+i] + p.b_U[fg*4+i]);
        } else {
          __syncthreads();                       // zt(y_new) visible in F layout
          #pragma unroll
          for (int i=0;i<4;++i) z4[i] = zt[rs*HID + fg*4 + i];
        }
        // LayerNorm over 128 features (32 fg lanes)
        {
          float sv=0.f, qv=0.f;
          #pragma unroll
          for (int i=0;i<4;++i){ sv+=z4[i]; qv+=z4[i]*z4[i]; }
          #pragma unroll
          for (int off=1; off<32; off<<=1){
            sv += __shfl_xor(sv, off); qv += __shfl_xor(qv, off);
          }
          float mu = sv*(1.f/HID);
          float r  = rsqrtf(qv*(1.f/HID) - mu*mu + 1e-5f);
          #pragma unroll
          for (int i=0;i<4;++i) z4[i] = (z4[i]-mu)*r;
        }
        __syncthreads();                         // all zt readers done
        *reinterpret_cast<float4*>(zt + rs*HID + fg*4) = make_float4(z4[0],z4[1],z4[2],z4[3]);
        if (last){
          if (actF)
            *reinterpret_cast<float4*>(p.y_out + (size_t)rowF*HID + fg*4) =
                make_float4(z4[0],z4[1],z4[2],z4[3]);
          // final stage: no more barriers; blocks exit uniformly
        } else {
          __syncthreads();                       // zt(z) visible
          if (idx > 0) load_WT_split(WbT, p.w_gat, tid);  // restore w_gat^T hi/lo
          #pragma unroll
          for (int i=0;i<8;++i) yb8[i] = zt[rA*HID + off8 + i];  // new y state (fp32)
          if (seg == 0) pack_y(yt_bf, rA, off8, yb8);
          __syncthreads();
          h_stage(yt_bf, ht_bf, WbT, mt, nt, quad, lc, fg, rs, rowF, actF, use_l2, h_wr, er_l, ar4, al4);
          grid_bar2(bar_b, NBLK_B * step, use_l2); ++step;
          rd ^= 1;
        }
      }
    }
  }
}

// out = tanh(ret @ w_o1 + b_o1) @ w_o2 + b_o2, fp32 output
__global__ void __launch_bounds__(256, 2) out_kernel(
    const float* __restrict__ y_base,
    const float* __restrict__ w_o1, const float* __restrict__ b_o1,
    const float* __restrict__ w_o2, const float* __restrict__ b_o2,
    float* __restrict__ out)
{
  __shared__ float Wl[HID*HID];
  __shared__ float yt[ORPB*HID];
  const int tid = threadIdx.x;
  const int row0 = blockIdx.x * ORPB;
  const int rA = tid >> 4, tA = tid & 15;
  const int rowA = row0 + rA;
  {
    float4 v0 = *reinterpret_cast<const float4*>(y_base + rowA*HID + tA*8);
    float4 v1 = *reinterpret_cast<const float4*>(y_base + rowA*HID + tA*8 + 4);
    *reinterpret_cast<float4*>(yt + rA*HID + tA*8)     = v0;
    *reinterpret_cast<float4*>(yt + rA*HID + tA*8 + 4) = v1;
  }
  load_W<256>(Wl, w_o1, tid);
  __syncthreads();
  const int fg = tid & 31, rs = tid >> 5;
  float t0[4], t1[4];
  gemm128<8>(Wl, yt, fg, rs, t0, t1);
  #pragma unroll
  for (int i=0;i<4;++i){
    float bb = b_o1[fg*4+i];
    t0[i] = tanhf(t0[i] + bb);
    t1[i] = tanhf(t1[i] + bb);
  }
  __syncthreads();
  *reinterpret_cast<float4*>(yt + rs*HID + fg*4)     = make_float4(t0[0],t0[1],t0[2],t0[3]);
  *reinterpret_cast<float4*>(yt + (rs+8)*HID + fg*4) = make_float4(t1[0],t1[1],t1[2],t1[3]);
  load_W<256>(Wl, w_o2, tid);
  __syncthreads();
  float o0[4], o1[4];
  gemm128<8>(Wl, yt, fg, rs, o0, o1);
  const int rowF0 = row0 + rs, rowF1 = row0 + rs + 8;
  *reinterpret_cast<float4*>(out + rowF0*HID + fg*4) =
      make_float4(o0[0]+b_o2[fg*4+0], o0[1]+b_o2[fg*4+1], o0[2]+b_o2[fg*4+2], o0[3]+b_o2[fg*4+3]);
  *reinterpret_cast<float4*>(out + rowF1*HID + fg*4) =
      make_float4(o1[0]+b_o2[fg*4+0], o1[1]+b_o2[fg*4+1], o1[2]+b_o2[fg*4+2], o1[3]+b_o2[fg*4+3]);
}

extern "C" void kernel_launch(void* const* d_in, const int* in_sizes, int n_in,
                              void* d_out, int out_size, void* d_ws, size_t ws_size,
                              hipStream_t stream)
{
  const float* inputs = (const float*)d_in[0];
  const int* src      = (const int*)d_in[1];
  const int* dst      = (const int*)d_in[2];
  const float* w_in   = (const float*)d_in[3];
  const float* b_in   = (const float*)d_in[4];
  const float* w_gat  = (const float*)d_in[5];
  const float* a_l    = (const float*)d_in[6];
  const float* a_r    = (const float*)d_in[7];
  const float* w_W    = (const float*)d_in[8];
  const float* b_W    = (const float*)d_in[9];
  const float* w_U    = (const float*)d_in[10];
  const float* b_U    = (const float*)d_in[11];
  const float* w_o1   = (const float*)d_in[12];
  const float* b_o1   = (const float*)d_in[13];
  const float* w_o2   = (const float*)d_in[14];
  const float* b_o2   = (const float*)d_in[15];

  const size_t RH  = (size_t)NROWS * HID;     // 1,024,000 (y_out floats)
  const size_t RH2 = (size_t)NROWS * HSTR;    // 1,152,000 (u16 per exchange buf)
  float* y_out = reinterpret_cast<float*>(d_ws);
  u16*   hbuf  = reinterpret_cast<u16*>(y_out + RH);
  u16*   hb0   = hbuf;
  u16*   hb1   = hbuf + RH2;
  int*   I     = reinterpret_cast<int*>(hbuf + 2*RH2);
  int* row_start = I;
  int* edge_src  = I + 1024;
  int* bar       = I + 1024 + NEDGE;

  size_t need = RH*sizeof(float) + 2*RH2*sizeof(u16)
              + (size_t)(1024 + NEDGE + NBATCH*BARSTRIDE)*sizeof(int);
  if (ws_size < need) return;

  csr_kernel<<<1, 1024, 0, stream>>>(src, dst, row_start, edge_src, bar);

  PArgs pa;
  pa.hb0 = hb0; pa.hb1 = hb1; pa.y_out = y_out;
  pa.row_start = row_start; pa.edge_src = edge_src;
  pa.w_gat = w_gat; pa.a_l = a_l; pa.a_r = a_r;
  pa.inputs = inputs; pa.w_in = w_in; pa.b_in = b_in;
  pa.w_W = w_W; pa.b_W = b_W; pa.w_U = w_U; pa.b_U = b_U;
  pa.bar = bar;

  persist<<<NBLK_P, PTHREADS, 0, stream>>>(pa);

  out_kernel<<<NBLK_O, 256, 0, stream>>>(y_out, w_o1, b_o1, w_o2, b_o2, (float*)d_out);
}

// Round 13
// 1710.766 us; speedup vs baseline: 3.5660x; 1.0081x over previous
//
#include <hip/hip_runtime.h>

#define NNODE 1000
#define NBATCH 8
#define SEQL 12
#define NHEAD 8
#define DHEAD 16
#define HID 128
#define NEDGE 16000
#define NROWS (NBATCH*NNODE)   // 8000
#define RPB 32                 // rows per persistent block
#define NBLK_P 256             // 8 batch-groups x 32 slots; 1 block/CU
#define NBLK_B 32              // blocks per batch = barrier width
#define BARSTRIDE 64           // ints between per-batch counters (256 B)
#define PTHREADS 1024
#define ORPB 16
#define NBLK_O (NROWS/ORPB)    // 500
#define DT 0.25f
#define ECAP 768               // LDS edge cache (block mean 512)
#define SPIN_LIMIT 2000000ULL  // 20 ms: transient slowness costs time, not NaN (R6)
#define WSTRIDE 136            // padded K-stride (u16, LDS tiles)
#define WLO (128*WSTRIDE)      // u16 offset of the lo-residual matrix
#define HSTR 144               // exchange row stride (u16): 128 bf16 h + 8 f32 el

// bar[] layout (ints), all zeroed by csr_kernel:
//   bat*64 + 0  : per-batch round counter
//   bat*64 + 32 : per-batch XCD mask
//   48          : global XCD mask   (batch0 stride area, unused offsets)
//   56          : startup barrier counter (256-wide)
#define OFF_MASK  32
#define OFF_GMASK 48
#define OFF_GCNT  56
#define HWREG_XCC_ID 6164      // s_getreg imm: id=20 (XCC_ID), offset=0, size=4

// Journal:
// R2  (XCD-L2 exchange + CAS-poll barrier): 2746 -> 1874 us. KEPT.
// R3  (edge-balanced LDS-atomic gather): 10x regression. REVERTED.
// R4/R6/R9 (deepen gather pipeline x3): dead on the 64-VGPR allocation.
// R5  (el precomputed, exchanged with h): -> 1744. KEPT.
// R7  (ht_bf split + MFMA 2-chain): -> 1733. KEPT.
// R8  (plain loads + per-round buffer_inv): -> 1731. KEPT.
// R10/R11 (2 blocks/CU occupancy play): dead — 2-block residency needs <=64
//    total regs, gather needs ~90; launch_bounds arg2 = min waves/EU.
// R12 (R8 restored): 1724.6, counters reproduced. BASE.
// R13 micros: (1) esrc_l holds precomputed u16-offsets (kills per-edge mul);
//    (2) buffer_inv moved inside grid_bar2, overlapped with the poll (safe:
//    no h loads between inv and barrier-pass; CAS doesn't fill vector L1);
//    (3) poll sleep 2->1. Structural interleaving analyzed and rejected:
//    needs barrier-wait > 4.5us, measured skew says ~0.5us.

typedef unsigned short u16;
typedef unsigned int   u32;
typedef unsigned long long u64;
typedef __attribute__((ext_vector_type(8))) short bf16x8;
typedef __attribute__((ext_vector_type(4))) float f32x4;
typedef __attribute__((ext_vector_type(4))) unsigned int u32x4;

__device__ __forceinline__ u16 f2bf(float f){
  u32 x = __float_as_uint(f);
  return (u16)((x + 0x7fffu + ((x>>16)&1u)) >> 16);
}
__device__ __forceinline__ float bf2f(u16 u){ return __uint_as_float(((u32)u)<<16); }

// ---- exchange primitives ----
// Agent path (MALL point-of-coherence): correct under ANY block->XCD mapping.
__device__ __forceinline__ u64 ld_agent_u64(const u16* p){
  return __hip_atomic_load(reinterpret_cast<const u64*>(p),
                           __ATOMIC_RELAXED, __HIP_MEMORY_SCOPE_AGENT);
}
__device__ __forceinline__ void st_agent_u64(u16* p, u64 v){
  __hip_atomic_store(reinterpret_cast<u64*>(p), v,
                     __ATOMIC_RELAXED, __HIP_MEMORY_SCOPE_AGENT);
}
__device__ __forceinline__ float ld_agent_f32(const float* p){
  u32 v = __hip_atomic_load(reinterpret_cast<const u32*>(p),
                            __ATOMIC_RELAXED, __HIP_MEMORY_SCOPE_AGENT);
  return __uint_as_float(v);
}
__device__ __forceinline__ void st_agent_f32(float* p, float v){
  __hip_atomic_store(reinterpret_cast<u32*>(p), __float_as_uint(v),
                     __ATOMIC_RELAXED, __HIP_MEMORY_SCOPE_AGENT);
}

// L1 invalidate (gfx940+): clears stale h lines in THIS CU's vector L1; plain
// loads then read current L2 (L1 is write-through). R8-proven coherent.
__device__ __forceinline__ void inv_l1(){
  asm volatile("buffer_inv sc0\n\ts_waitcnt vmcnt(0)" ::: "memory");
}

// L2-barrier poll: failing CAS executed at the XCD TCC atomic unit returns the
// current counter value — meets the fetch_add increments at the same unit.
__device__ __forceinline__ int poll_l2(int* p){
  int exp = -1;                     // counter is never -1
  __hip_atomic_compare_exchange_strong(p, &exp, -1,
      __ATOMIC_RELAXED, __ATOMIC_RELAXED, __HIP_MEMORY_SCOPE_WORKGROUP);
  return exp;
}

// ---- barriers ----
// L2 path: arrive, then ALL waves run buffer_inv (overlaps tid0's poll; safe
// because no h loads occur until after the closing sync, and the poll's CAS
// doesn't populate the vector L1 with h lines), then poll, then sync.
__device__ __forceinline__ void grid_bar2(int* bar, int target, bool l2){
  __syncthreads();   // drains each wave's stores (vmcnt 0) before arrival
  if (l2){
    if (threadIdx.x == 0)
      __hip_atomic_fetch_add(bar, 1, __ATOMIC_RELAXED, __HIP_MEMORY_SCOPE_WORKGROUP);
    inv_l1();        // per-wave; runs while arrivals accumulate
    if (threadIdx.x == 0){
      unsigned long long t0 = __builtin_amdgcn_s_memrealtime();
      while (poll_l2(bar) < target){
        __builtin_amdgcn_s_sleep(1);
        if (__builtin_amdgcn_s_memrealtime() - t0 > SPIN_LIMIT) break;
      }
    }
  } else {
    if (threadIdx.x == 0){
      __hip_atomic_fetch_add(bar, 1, __ATOMIC_RELEASE, __HIP_MEMORY_SCOPE_AGENT);
      unsigned long long t0 = __builtin_amdgcn_s_memrealtime();
      while (__hip_atomic_load(bar, __ATOMIC_RELAXED, __HIP_MEMORY_SCOPE_AGENT) < target){
        __builtin_amdgcn_s_sleep(2);
        if (__builtin_amdgcn_s_memrealtime() - t0 > SPIN_LIMIT) break;
      }
    }
  }
  __syncthreads();
}

// one-time 256-block agent barrier (orders initial h stores + XCD-mask ORs)
__device__ __forceinline__ void startup_bar(int* cnt){
  __syncthreads();
  if (threadIdx.x == 0){
    __hip_atomic_fetch_add(cnt, 1, __ATOMIC_RELEASE, __HIP_MEMORY_SCOPE_AGENT);
    unsigned long long t0 = __builtin_amdgcn_s_memrealtime();
    while (__hip_atomic_load(cnt, __ATOMIC_RELAXED, __HIP_MEMORY_SCOPE_AGENT) < NBLK_P){
      __builtin_amdgcn_s_sleep(2);
      if (__builtin_amdgcn_s_memrealtime() - t0 > SPIN_LIMIT) break;
    }
  }
  __syncthreads();
}

// copy a 128x128 fp32 matrix global->LDS, NT threads (GRU + out_kernel path)
template<int NT>
__device__ __forceinline__ void load_W(float* Wl, const float* g, int tid){
  #pragma unroll
  for (int c = 0; c < (HID*HID/4)/NT; ++c){
    int e = (c*NT + tid)*4;
    *reinterpret_cast<float4*>(Wl + e) = *reinterpret_cast<const float4*>(g + e);
  }
}

// split-precision transposed load: W[k][n] fp32 -> WbT[n][k] hi/lo bf16
__device__ __forceinline__ void load_WT_split(u16* WbT, const float* g, int tid){
  #pragma unroll
  for (int c = 0; c < 16; ++c){
    int flat = c*PTHREADS + tid;        // = k*128 + n
    int k = flat >> 7, n = flat & 127;
    float v = g[flat];
    u16 hi = f2bf(v);
    u16 lo = f2bf(v - bf2f(hi));
    WbT[n*WSTRIDE + k]       = hi;
    WbT[WLO + n*WSTRIDE + k] = lo;
  }
}

// one row, 4 cols: o[j] = sum_k yt[rs][k]*Wl[k][fg*4+j]  (fp32, GRU path)
__device__ __forceinline__ void gemm128_1(const float* Wl, const float* yt, int fg, int rs,
                                          float o[4]){
  float a0[4]={0.f,0.f,0.f,0.f};
  #pragma unroll 4
  for (int k=0;k<HID;k+=4){
    float4 ya = *reinterpret_cast<const float4*>(yt + rs*HID + k);
    #pragma unroll
    for (int kk=0;kk<4;++kk){
      const float* wr = Wl + (k+kk)*HID + fg*4;
      float av = (&ya.x)[kk];
      #pragma unroll
      for (int i=0;i<4;++i) a0[i] = fmaf(wr[i], av, a0[i]);
    }
  }
  #pragma unroll
  for (int i=0;i<4;++i) o[i]=a0[i];
}

// two rows (rs, rs+RSTEP), 4 cols — used by out_kernel
template<int RSTEP>
__device__ __forceinline__ void gemm128(const float* Wl, const float* yt, int fg, int rs,
                                        float o0[4], float o1[4]){
  float a0[4]={0.f,0.f,0.f,0.f}, a1[4]={0.f,0.f,0.f,0.f};
  #pragma unroll 4
  for (int k=0;k<HID;k+=4){
    float4 ya = *reinterpret_cast<const float4*>(yt + rs*HID + k);
    float4 yb = *reinterpret_cast<const float4*>(yt + (rs+RSTEP)*HID + k);
    #pragma unroll
    for (int kk=0;kk<4;++kk){
      const float* wr = Wl + (k+kk)*HID + fg*4;
      float av = (&ya.x)[kk];
      float bv = (&yb.x)[kk];
      #pragma unroll
      for (int i=0;i<4;++i){
        float w = wr[i];
        a0[i] = fmaf(w, av, a0[i]);
        a1[i] = fmaf(w, bv, a1[i]);
      }
    }
  }
  #pragma unroll
  for (int i=0;i<4;++i){ o0[i]=a0[i]; o1[i]=a1[i]; }
}

// pack 8 fp32 -> 8 bf16 into yt_bf[rA][off8..off8+7]
__device__ __forceinline__ void pack_y(u16* yt_bf, int rA, int off8, const float y[8]){
  uint4 w;
  w.x = (u32)f2bf(y[0]) | ((u32)f2bf(y[1])<<16);
  w.y = (u32)f2bf(y[2]) | ((u32)f2bf(y[3])<<16);
  w.z = (u32)f2bf(y[4]) | ((u32)f2bf(y[5])<<16);
  w.w = (u32)f2bf(y[6]) | ((u32)f2bf(y[7])<<16);
  *reinterpret_cast<uint4*>(yt_bf + rA*WSTRIDE + off8) = w;
}

// per-edge decode + attention + register accumulate. el precomputed (h_stage),
// so the weight is a short chain: add -> leaky -> exp. No cross-lane ops.
__device__ __forceinline__ void edge_acc(const u32x4 q, float el, float erh,
                                         float acc[8], float& sum){
  float hv[8];
  hv[0]=__uint_as_float(q[0]<<16); hv[1]=__uint_as_float(q[0]&0xffff0000u);
  hv[2]=__uint_as_float(q[1]<<16); hv[3]=__uint_as_float(q[1]&0xffff0000u);
  hv[4]=__uint_as_float(q[2]<<16); hv[5]=__uint_as_float(q[2]&0xffff0000u);
  hv[6]=__uint_as_float(q[3]<<16); hv[7]=__uint_as_float(q[3]&0xffff0000u);
  const float x = el + erh;
  const float w = __expf(fminf(fmaxf(x, 0.2f*x), 30.f));
  sum += w;
  #pragma unroll
  for (int i=0;i<8;++i) acc[i] = fmaf(w, hv[i], acc[i]);
}

// gather over this thread's edge range; eoffs holds PRECOMPUTED u16-element
// offsets into the exchange buffer ((sbase+src)*HSTR) — no per-edge multiply.
// L2=true : plain loads (L1 was invalidated at the barrier; L1 is WT).
// L2=false: agent-scope loads (any XCD mapping).
template<bool L2>
__device__ __forceinline__ void gather_f(const u16* __restrict__ h_rd,
    const int* __restrict__ eoffs, int e_lo, int e_hi, int off8, int hd,
    float erh, float acc[8], float& sum)
{
  if constexpr (L2){
    int e = e_lo;
    for (; e + 4 <= e_hi; e += 4){
      const u16* r0 = h_rd + eoffs[e+0];
      const u16* r1 = h_rd + eoffs[e+1];
      const u16* r2 = h_rd + eoffs[e+2];
      const u16* r3 = h_rd + eoffs[e+3];
      u32x4 q0 = *reinterpret_cast<const u32x4*>(r0 + off8);
      u32x4 q1 = *reinterpret_cast<const u32x4*>(r1 + off8);
      u32x4 q2 = *reinterpret_cast<const u32x4*>(r2 + off8);
      u32x4 q3 = *reinterpret_cast<const u32x4*>(r3 + off8);
      float x0 = reinterpret_cast<const float*>(r0 + 128)[hd];
      float x1 = reinterpret_cast<const float*>(r1 + 128)[hd];
      float x2 = reinterpret_cast<const float*>(r2 + 128)[hd];
      float x3 = reinterpret_cast<const float*>(r3 + 128)[hd];
      edge_acc(q0, x0, erh, acc, sum);
      edge_acc(q1, x1, erh, acc, sum);
      edge_acc(q2, x2, erh, acc, sum);
      edge_acc(q3, x3, erh, acc, sum);
    }
    for (; e < e_hi; ++e){
      const u16* r = h_rd + eoffs[e];
      u32x4 q = *reinterpret_cast<const u32x4*>(r + off8);
      float x = reinterpret_cast<const float*>(r + 128)[hd];
      edge_acc(q, x, erh, acc, sum);
    }
  } else {
    for (int e = e_lo; e < e_hi; ++e){
      const u16* r = h_rd + eoffs[e];
      const u64 L = ld_agent_u64(r + off8);
      const u64 H = ld_agent_u64(r + off8 + 4);
      const float x = ld_agent_f32(reinterpret_cast<const float*>(r + 128) + hd);
      u32x4 v;
      v[0]=(u32)L; v[1]=(u32)(L>>32); v[2]=(u32)H; v[3]=(u32)(H>>32);
      edge_acc(v, x, erh, acc, sum);
    }
  }
}

// statistically-never fallback (edge list exceeds LDS cache): agent loads,
// raw node ids from global CSR. Correctness only.
__device__ __forceinline__ void gather_fb(const u16* __restrict__ h_rd,
    const int* __restrict__ eids, int e_lo, int e_hi, int sbase, int off8, int hd,
    float erh, float acc[8], float& sum)
{
  for (int e = e_lo; e < e_hi; ++e){
    const u16* r = h_rd + (size_t)(sbase + eids[e])*HSTR;
    const u64 L = ld_agent_u64(r + off8);
    const u64 H = ld_agent_u64(r + off8 + 4);
    const float x = ld_agent_f32(reinterpret_cast<const float*>(r + 128) + hd);
    u32x4 v;
    v[0]=(u32)L; v[1]=(u32)(L>>32); v[2]=(u32)H; v[3]=(u32)(H>>32);
    edge_acc(v, x, erh, acc, sum);
  }
}

// MFMA h-stage: yt_bf holds y (bf16, read-only here); h goes to ht_bf
// (separate buffer -> one fewer sync: no WAR on yt_bf). Two accumulator
// chains halve dependent-MFMA latency. Wire-stores packed u64 h + fp32 el.
__device__ __forceinline__ void h_stage(const u16* yt_bf, u16* ht_bf, const u16* WbT,
    int mt, int nt, int quad, int lc,
    int fg, int rs, int rowF, bool actF, bool l2,
    u16* __restrict__ h_wr, float* er_l, const float ar4[4], const float al4[4])
{
  f32x4 c0 = {0.f,0.f,0.f,0.f}, c1 = {0.f,0.f,0.f,0.f};
  const u16* arow = yt_bf + (mt*16 + lc)*WSTRIDE;
  const u16* brow = WbT  + (nt*16 + lc)*WSTRIDE;
  #pragma unroll
  for (int k0 = 0; k0 < 4; ++k0){
    const int off = k0*32 + quad*8;
    bf16x8 a  = *reinterpret_cast<const bf16x8*>(arow + off);
    bf16x8 bh = *reinterpret_cast<const bf16x8*>(brow + off);
    bf16x8 bl = *reinterpret_cast<const bf16x8*>(brow + WLO + off);
    if (k0 & 1){
      c1 = __builtin_amdgcn_mfma_f32_16x16x32_bf16(a, bh, c1, 0, 0, 0);
      c1 = __builtin_amdgcn_mfma_f32_16x16x32_bf16(a, bl, c1, 0, 0, 0);
    } else {
      c0 = __builtin_amdgcn_mfma_f32_16x16x32_bf16(a, bh, c0, 0, 0, 0);
      c0 = __builtin_amdgcn_mfma_f32_16x16x32_bf16(a, bl, c0, 0, 0, 0);
    }
  }
  {
    const int col = nt*16 + lc;
    #pragma unroll
    for (int r = 0; r < 4; ++r)
      ht_bf[(mt*16 + quad*4 + r)*WSTRIDE + col] = f2bf(c0[r] + c1[r]);
  }
  __syncthreads();              // h bf16 visible block-wide
  const u64 pk = *reinterpret_cast<const u64*>(ht_bf + rs*WSTRIDE + fg*4);
  if (actF){
    if (l2) *reinterpret_cast<u64*>(h_wr + (size_t)rowF*HSTR + fg*4) = pk;
    else    st_agent_u64(h_wr + (size_t)rowF*HSTR + fg*4, pk);
  }
  const float h0 = bf2f((u16)pk),       h1 = bf2f((u16)(pk>>16));
  const float h2 = bf2f((u16)(pk>>32)), h3 = bf2f((u16)(pk>>48));
  float er = 0.f, el = 0.f;
  er = fmaf(h0, ar4[0], er); er = fmaf(h1, ar4[1], er);
  er = fmaf(h2, ar4[2], er); er = fmaf(h3, ar4[3], er);
  el = fmaf(h0, al4[0], el); el = fmaf(h1, al4[1], el);
  el = fmaf(h2, al4[2], el); el = fmaf(h3, al4[3], el);
  er += __shfl_xor(er,1); er += __shfl_xor(er,2);
  el += __shfl_xor(el,1); el += __shfl_xor(el,2);
  if ((fg & 3) == 0 && actF){
    er_l[rs*NHEAD + (fg>>2)] = er;
    float* elp = reinterpret_cast<float*>(h_wr + (size_t)rowF*HSTR + 128);
    if (l2) elp[fg>>2] = el;
    else    st_agent_f32(elp + (fg>>2), el);
  }
}

// Build CSR (edges sorted by dst); zero the per-batch barrier area.
__global__ void csr_kernel(const int* __restrict__ src, const int* __restrict__ dst,
                           int* __restrict__ row_start, int* __restrict__ edge_src,
                           int* __restrict__ bar){
  __shared__ int cnt[1024];
  __shared__ int scanb[1024];
  __shared__ int cur[1024];
  int tid = threadIdx.x;
  if (tid < NBATCH*BARSTRIDE) bar[tid] = 0;
  cnt[tid] = 0;
  __syncthreads();
  for (int e = tid; e < NEDGE; e += 1024) atomicAdd(&cnt[dst[e]], 1);
  __syncthreads();
  int v = cnt[tid];
  scanb[tid] = v;
  __syncthreads();
  for (int off=1; off<1024; off<<=1){
    int t = (tid >= off) ? scanb[tid-off] : 0;
    __syncthreads();
    scanb[tid] += t;
    __syncthreads();
  }
  int incl = scanb[tid];
  if (tid < NNODE){ cur[tid] = incl - v; row_start[tid+1] = incl; }
  if (tid == 0) row_start[0] = 0;
  __syncthreads();
  for (int e = tid; e < NEDGE; e += 1024){
    int d = dst[e];
    int pos = atomicAdd(&cur[d], 1);
    edge_src[pos] = src[e];
  }
}

struct PArgs {
  u16* hb0; u16* hb1; float* y_out;
  const int* row_start; const int* edge_src;
  const float* w_gat; const float* a_l; const float* a_r;
  const float* inputs; const float* w_in; const float* b_in;
  const float* w_W; const float* b_W; const float* w_U; const float* b_U;
  int* bar;
};

__global__ void __launch_bounds__(PTHREADS, 4) persist(PArgs p)
{
  __shared__ __align__(16) u16 WbT[2*128*WSTRIDE];  // 68 KB: w_gat^T hi/lo (bf16)
  __shared__ __align__(16) u16 yt_bf[RPB*WSTRIDE];  // 8.5 KB: y (bf16)
  __shared__ __align__(16) u16 ht_bf[RPB*WSTRIDE];  // 8.5 KB: h (bf16)
  __shared__ float zt[RPB*HID];                     // 16 KB: fp32 GRU/LN staging
  __shared__ int   esrc_l[ECAP];                    // precomputed u16-offsets
  __shared__ int   eoff[RPB+1];
  __shared__ int   degs_s[RPB];
  __shared__ float er_l[RPB*NHEAD];                 // total ~106 KB -> 1 block/CU
  __shared__ int   use_l2_s;
  float* const Wlf = reinterpret_cast<float*>(WbT); // 64 KB fp32 overlay (GRU)

  const int tid  = threadIdx.x;
  const int bat   = blockIdx.x & 7;            // batch index (XCD heuristic)
  const int slot  = blockIdx.x >> 3;           // 0..31
  const int row0  = bat * NNODE + slot * RPB;
  const int nrows = (slot == 31) ? (NNODE - 31*RPB) : RPB;   // 8 or 32
  int* const bar_b = p.bar + bat * BARSTRIDE;
  // layout A (gather): 16 threads x 2 edge-segments per row, 32 rows
  const int tA = tid & 15, seg = (tid >> 4) & 1, rA = tid >> 5;
  const bool actA = rA < nrows;
  const int nA     = slot*RPB + rA;
  const int nAs    = actA ? nA : 0;
  const int sbase  = bat * NNODE;
  const int hd   = tA >> 1;
  const int off8 = tA * 8;
  // layout F (epilogue/LN): 32 col-groups (4 cols) x 32 rows
  const int fg = tid & 31, rs = tid >> 5;
  const bool actF = rs < nrows;
  const int rowF = row0 + rs;
  const int hd2 = fg >> 2, db = (fg & 3) * 4;
  // MFMA ids: 16 waves = 2 M-tiles x 8 N-tiles
  const int wv = tid >> 6, lane = tid & 63, quad = lane >> 4, lc = lane & 15;
  const int mt = wv & 1, nt = wv >> 1;

  // ---- one-time: per-block edge cache (PRECOMPUTED u16-element offsets) ----
  int s0r = 0, degr = 0;
  if (actA){ s0r = p.row_start[nA]; degr = p.row_start[nA+1] - s0r; }
  if ((tid & 31) == 0) degs_s[rA] = degr;
  __syncthreads();
  if (tid == 0){
    int o = 0;
    #pragma unroll
    for (int r = 0; r < RPB; ++r){ eoff[r] = o; o += degs_s[r]; }
    eoff[RPB] = o;
  }
  __syncthreads();
  const bool cached = (eoff[RPB] <= ECAP);
  const int* eptr = nullptr;
  if (cached){
    const int eb = eoff[rA];
    for (int e = tA + 16*seg; e < degr; e += 32)
      esrc_l[eb + e] = (sbase + p.edge_src[s0r + e]) * HSTR;
    eptr = esrc_l + eb;
  }
  const int* const eptr_g = p.edge_src + s0r;   // fallback (raw ids)

  // ---- one-time: per-thread constants ----
  float ar4[4], al4[4];
  #pragma unroll
  for (int i=0;i<4;++i){
    ar4[i] = p.a_r[hd2*DHEAD + db + i];
    al4[i] = p.a_l[hd2*DHEAD + db + i];
  }

  load_WT_split(WbT, p.w_gat, tid);

  // ---- init: y0 = inputs[:,0]@w_in + b_in ----
  float yb8[8], ya8[8];
  {
    const float x0 = p.inputs[((bat*SEQL + 0)*NNODE + nAs)*2 + 0];
    const float x1 = p.inputs[((bat*SEQL + 0)*NNODE + nAs)*2 + 1];
    #pragma unroll
    for (int i=0;i<8;++i){
      int f = off8 + i;
      yb8[i] = x0*p.w_in[f] + x1*p.w_in[HID+f] + p.b_in[f];
    }
    if (seg == 0) pack_y(yt_bf, rA, off8, yb8);
  }
  __syncthreads();     // yt_bf, WbT, esrc_l staged
  // initial h store goes agent-scope (path not decided yet; safe either way)
  h_stage(yt_bf, ht_bf, WbT, mt, nt, quad, lc, fg, rs, rowF, actF, false, p.hb0, er_l, ar4, al4);

  // ---- XCD-locality detection + 256-wide startup barrier ----
  // use_l2 requires: all 32 blocks of this batch on ONE XCD (popc==1) AND the
  // register genuinely distinguishing 8 XCDs chip-wide (popc==8) — a bogus/
  // constant hwreg read yields global popc 1 -> safe fallback to agent path.
  if (tid == 0){
    int xcc = (int)(__builtin_amdgcn_s_getreg(HWREG_XCC_ID) & 0xf);
    __hip_atomic_fetch_or(reinterpret_cast<u32*>(bar_b + OFF_MASK), 1u<<xcc,
                          __ATOMIC_RELAXED, __HIP_MEMORY_SCOPE_AGENT);
    __hip_atomic_fetch_or(reinterpret_cast<u32*>(p.bar + OFF_GMASK), 1u<<xcc,
                          __ATOMIC_RELAXED, __HIP_MEMORY_SCOPE_AGENT);
  }
  startup_bar(p.bar + OFF_GCNT);    // also publishes hb0 + masks everywhere
  if (tid == 0){
    u32 mb = __hip_atomic_load(reinterpret_cast<u32*>(bar_b + OFF_MASK),
                               __ATOMIC_RELAXED, __HIP_MEMORY_SCOPE_AGENT);
    u32 mg = __hip_atomic_load(reinterpret_cast<u32*>(p.bar + OFF_GMASK),
                               __ATOMIC_RELAXED, __HIP_MEMORY_SCOPE_AGENT);
    use_l2_s = (__popc(mb) == 1 && __popc(mg) == 8) ? 1 : 0;
  }
  __syncthreads();
  const bool use_l2 = use_l2_s != 0;
  inv_l1();            // first-round coverage (later invs live in grid_bar2)

  int step = 1;

  // per-segment edge range (contiguous halves)
  const int half0 = (degr + 1) >> 1;
  const int e_lo = seg ? half0 : 0;
  const int e_hi = seg ? degr  : half0;

  int rd = 0;
  for (int idx = 0; idx < SEQL; ++idx){
    for (int st = 0; st < 4; ++st){
      for (int j = 1; j <= 4; ++j){
        const u16* __restrict__ h_rd = rd ? p.hb1 : p.hb0;
        u16* __restrict__ h_wr       = rd ? p.hb0 : p.hb1;

        // ---- gather: softmax aggregation; el/er precomputed in h_stage ----
        float acc[8] = {0.f,0.f,0.f,0.f,0.f,0.f,0.f,0.f};
        float sum = 0.f;
        {
          const float erh = er_l[rA*NHEAD + hd];
          if (cached){
            if (use_l2)
              gather_f<true >(h_rd, eptr, e_lo, e_hi, off8, hd, erh, acc, sum);
            else
              gather_f<false>(h_rd, eptr, e_lo, e_hi, off8, hd, erh, acc, sum);
          } else {
            gather_fb(h_rd, eptr_g, e_lo, e_hi, sbase, off8, hd, erh, acc, sum);
          }
        }
        sum += __shfl_xor(sum, 16);
        #pragma unroll
        for (int i=0;i<8;++i) acc[i] += __shfl_xor(acc[i], 16);
        const float inv = 1.f / (sum + 1e-16f);
        #pragma unroll
        for (int i=0;i<8;++i) acc[i] *= inv;

        // ---- RK4 register update ----
        const bool is5 = (st == 3) && (j == 4);
        float nxt[8];
        if (j == 1){
          #pragma unroll
          for (int i=0;i<8;++i){ ya8[i] = fmaf(DT/6.f, acc[i], yb8[i]);
                                 nxt[i] = fmaf(0.5f*DT, acc[i], yb8[i]); }
        } else if (j == 2){
          #pragma unroll
          for (int i=0;i<8;++i){ ya8[i] = fmaf(DT/3.f, acc[i], ya8[i]);
                                 nxt[i] = fmaf(0.5f*DT, acc[i], yb8[i]); }
        } else if (j == 3){
          #pragma unroll
          for (int i=0;i<8;++i){ ya8[i] = fmaf(DT/3.f, acc[i], ya8[i]);
                                 nxt[i] = fmaf(DT, acc[i], yb8[i]); }
        } else {
          #pragma unroll
          for (int i=0;i<8;++i) nxt[i] = fmaf(DT/6.f, acc[i], ya8[i]);
          if (!is5){
            #pragma unroll
            for (int i=0;i<8;++i) yb8[i] = nxt[i];
          }
        }

        if (!is5){
          if (seg == 0) pack_y(yt_bf, rA, off8, nxt);
          __syncthreads();
          h_stage(yt_bf, ht_bf, WbT, mt, nt, quad, lc, fg, rs, rowF, actF, use_l2, h_wr, er_l, ar4, al4);
          grid_bar2(bar_b, NBLK_B * step, use_l2); ++step;
          rd ^= 1;
          continue;
        }

        // ---- end of interval: GRU (fp32 vector) / LN / state handoff ----
        const bool last = (idx == SEQL-1);
        if (seg == 0){
          *reinterpret_cast<float4*>(zt + rA*HID + off8)     = make_float4(nxt[0],nxt[1],nxt[2],nxt[3]);
          *reinterpret_cast<float4*>(zt + rA*HID + off8 + 4) = make_float4(nxt[4],nxt[5],nxt[6],nxt[7]);
        }
        float z4[4];
        if (idx > 0){
          load_W<PTHREADS>(Wlf, p.w_W, tid);     // overlays WbT (restored below)
          __syncthreads();                       // zt(y_new) + w_W ready
          gemm128_1(Wlf, zt, fg, rs, z4);        // z = y_new @ w_W
          __syncthreads();                       // gemm reads done
          {
            const float x0 = p.inputs[((bat*SEQL + idx)*NNODE + nAs)*2 + 0];
            const float x1 = p.inputs[((bat*SEQL + idx)*NNODE + nAs)*2 + 1];
            if (seg == 0){
              float hv[8];
              #pragma unroll
              for (int i=0;i<8;++i){
                int f = off8 + i;
                hv[i] = x0*p.w_in[f] + x1*p.w_in[HID+f] + p.b_in[f];
              }
              *reinterpret_cast<float4*>(zt + rA*HID + off8)     = make_float4(hv[0],hv[1],hv[2],hv[3]);
              *reinterpret_cast<float4*>(zt + rA*HID + off8 + 4) = make_float4(hv[4],hv[5],hv[6],hv[7]);
            }
          }
          load_W<PTHREADS>(Wlf, p.w_U, tid);
          __syncthreads();
          float u4[4];
          gemm128_1(Wlf, zt, fg, rs, u4);        // u = h_in @ w_U
          #pragma unroll
          for (int i=0;i<4;++i)
            z4[i] = tanhf(z4[i] + u4[i] + p.b_W[fg*4+i] + p.b_U[fg*4+i]);
        } else {
          __syncthreads();                       // zt(y_new) visible in F layout
          #pragma unroll
          for (int i=0;i<4;++i) z4[i] = zt[rs*HID + fg*4 + i];
        }
        // LayerNorm over 128 features (32 fg lanes)
        {
          float sv=0.f, qv=0.f;
          #pragma unroll
          for (int i=0;i<4;++i){ sv+=z4[i]; qv+=z4[i]*z4[i]; }
          #pragma unroll
          for (int off=1; off<32; off<<=1){
            sv += __shfl_xor(sv, off); qv += __shfl_xor(qv, off);
          }
          float mu = sv*(1.f/HID);
          float r  = rsqrtf(qv*(1.f/HID) - mu*mu + 1e-5f);
          #pragma unroll
          for (int i=0;i<4;++i) z4[i] = (z4[i]-mu)*r;
        }
        __syncthreads();                         // all zt readers done
        *reinterpret_cast<float4*>(zt + rs*HID + fg*4) = make_float4(z4[0],z4[1],z4[2],z4[3]);
        if (last){
          if (actF)
            *reinterpret_cast<float4*>(p.y_out + (size_t)rowF*HID + fg*4) =
                make_float4(z4[0],z4[1],z4[2],z4[3]);
          // final stage: no more barriers; blocks exit uniformly
        } else {
          __syncthreads();                       // zt(z) visible
          if (idx > 0) load_WT_split(WbT, p.w_gat, tid);  // restore w_gat^T hi/lo
          #pragma unroll
          for (int i=0;i<8;++i) yb8[i] = zt[rA*HID + off8 + i];  // new y state (fp32)
          if (seg == 0) pack_y(yt_bf, rA, off8, yb8);
          __syncthreads();
          h_stage(yt_bf, ht_bf, WbT, mt, nt, quad, lc, fg, rs, rowF, actF, use_l2, h_wr, er_l, ar4, al4);
          grid_bar2(bar_b, NBLK_B * step, use_l2); ++step;
          rd ^= 1;
        }
      }
    }
  }
}

// out = tanh(ret @ w_o1 + b_o1) @ w_o2 + b_o2, fp32 output
__global__ void __launch_bounds__(256, 2) out_kernel(
    const float* __restrict__ y_base,
    const float* __restrict__ w_o1, const float* __restrict__ b_o1,
    const float* __restrict__ w_o2, const float* __restrict__ b_o2,
    float* __restrict__ out)
{
  __shared__ float Wl[HID*HID];
  __shared__ float yt[ORPB*HID];
  const int tid = threadIdx.x;
  const int row0 = blockIdx.x * ORPB;
  const int rA = tid >> 4, tA = tid & 15;
  const int rowA = row0 + rA;
  {
    float4 v0 = *reinterpret_cast<const float4*>(y_base + rowA*HID + tA*8);
    float4 v1 = *reinterpret_cast<const float4*>(y_base + rowA*HID + tA*8 + 4);
    *reinterpret_cast<float4*>(yt + rA*HID + tA*8)     = v0;
    *reinterpret_cast<float4*>(yt + rA*HID + tA*8 + 4) = v1;
  }
  load_W<256>(Wl, w_o1, tid);
  __syncthreads();
  const int fg = tid & 31, rs = tid >> 5;
  float t0[4], t1[4];
  gemm128<8>(Wl, yt, fg, rs, t0, t1);
  #pragma unroll
  for (int i=0;i<4;++i){
    float bb = b_o1[fg*4+i];
    t0[i] = tanhf(t0[i] + bb);
    t1[i] = tanhf(t1[i] + bb);
  }
  __syncthreads();
  *reinterpret_cast<float4*>(yt + rs*HID + fg*4)     = make_float4(t0[0],t0[1],t0[2],t0[3]);
  *reinterpret_cast<float4*>(yt + (rs+8)*HID + fg*4) = make_float4(t1[0],t1[1],t1[2],t1[3]);
  load_W<256>(Wl, w_o2, tid);
  __syncthreads();
  float o0[4], o1[4];
  gemm128<8>(Wl, yt, fg, rs, o0, o1);
  const int rowF0 = row0 + rs, rowF1 = row0 + rs + 8;
  *reinterpret_cast<float4*>(out + rowF0*HID + fg*4) =
      make_float4(o0[0]+b_o2[fg*4+0], o0[1]+b_o2[fg*4+1], o0[2]+b_o2[fg*4+2], o0[3]+b_o2[fg*4+3]);
  *reinterpret_cast<float4*>(out + rowF1*HID + fg*4) =
      make_float4(o1[0]+b_o2[fg*4+0], o1[1]+b_o2[fg*4+1], o1[2]+b_o2[fg*4+2], o1[3]+b_o2[fg*4+3]);
}

extern "C" void kernel_launch(void* const* d_in, const int* in_sizes, int n_in,
                              void* d_out, int out_size, void* d_ws, size_t ws_size,
                              hipStream_t stream)
{
  const float* inputs = (const float*)d_in[0];
  const int* src      = (const int*)d_in[1];
  const int* dst      = (const int*)d_in[2];
  const float* w_in   = (const float*)d_in[3];
  const float* b_in   = (const float*)d_in[4];
  const float* w_gat  = (const float*)d_in[5];
  const float* a_l    = (const float*)d_in[6];
  const float* a_r    = (const float*)d_in[7];
  const float* w_W    = (const float*)d_in[8];
  const float* b_W    = (const float*)d_in[9];
  const float* w_U    = (const float*)d_in[10];
  const float* b_U    = (const float*)d_in[11];
  const float* w_o1   = (const float*)d_in[12];
  const float* b_o1   = (const float*)d_in[13];
  const float* w_o2   = (const float*)d_in[14];
  const float* b_o2   = (const float*)d_in[15];

  const size_t RH  = (size_t)NROWS * HID;     // 1,024,000 (y_out floats)
  const size_t RH2 = (size_t)NROWS * HSTR;    // 1,152,000 (u16 per exchange buf)
  float* y_out = reinterpret_cast<float*>(d_ws);
  u16*   hbuf  = reinterpret_cast<u16*>(y_out + RH);
  u16*   hb0   = hbuf;
  u16*   hb1   = hbuf + RH2;
  int*   I     = reinterpret_cast<int*>(hbuf + 2*RH2);
  int* row_start = I;
  int* edge_src  = I + 1024;
  int* bar       = I + 1024 + NEDGE;

  size_t need = RH*sizeof(float) + 2*RH2*sizeof(u16)
              + (size_t)(1024 + NEDGE + NBATCH*BARSTRIDE)*sizeof(int);
  if (ws_size < need) return;

  csr_kernel<<<1, 1024, 0, stream>>>(src, dst, row_start, edge_src, bar);

  PArgs pa;
  pa.hb0 = hb0; pa.hb1 = hb1; pa.y_out = y_out;
  pa.row_start = row_start; pa.edge_src = edge_src;
  pa.w_gat = w_gat; pa.a_l = a_l; pa.a_r = a_r;
  pa.inputs = inputs; pa.w_in = w_in; pa.b_in = b_in;
  pa.w_W = w_W; pa.b_W = b_W; pa.w_U = w_U; pa.b_U = b_U;
  pa.bar = bar;

  persist<<<NBLK_P, PTHREADS, 0, stream>>>(pa);

  out_kernel<<<NBLK_O, 256, 0, stream>>>(y_out, w_o1, b_o1, w_o2, b_o2, (float*)d_out);
}